// Round 6
// baseline (440.183 us; speedup 1.0000x reference)
//
#include <hip/hip_runtime.h>

#define CH 128
#define BCHUNK 4096   // edges per binning block (16 per thread @ 256 thr)
#define NB 256        // max buckets

typedef float f32x4 __attribute__((ext_vector_type(4)));
typedef short s16x8 __attribute__((ext_vector_type(8)));

// ---------------- edge dtype detection (int32 vs int64) ----------------
__global__ void detect_kernel(const int* __restrict__ ei, int* __restrict__ flag, int nwords) {
    int i = blockIdx.x * blockDim.x + threadIdx.x;
    int w = 2 * i + 1;
    if (w < nwords) {
        if (ei[w] != 0) atomicOr(flag, 1);
    }
}

__device__ __forceinline__ int edge_at(const void* ei, int idx, int is64) {
    if (is64) return (int)((const long long*)ei)[idx];
    return ((const int*)ei)[idx];
}

// ---------------- CSR build pass A: histogram / scans / bin ----------------
__global__ __launch_bounds__(256) void hist_kernel(const void* __restrict__ ei,
                                                   const int* __restrict__ flag,
                                                   int* __restrict__ hist, int e, int shift) {
    __shared__ int h[NB];
    h[threadIdx.x] = 0;
    __syncthreads();
    int is64 = (*flag == 0);
    int base = blockIdx.x * BCHUNK;
    #pragma unroll
    for (int k = 0; k < BCHUNK / 256; ++k) {
        int i = base + k * 256 + threadIdx.x;
        if (i < e) {
            int d = edge_at(ei, e + i, is64);
            atomicAdd(&h[d >> shift], 1);
        }
    }
    __syncthreads();
    hist[blockIdx.x * NB + threadIdx.x] = h[threadIdx.x];
}

// per-bucket exclusive scan over blocks (column scan); also bucket totals
__global__ __launch_bounds__(512) void scan_col_kernel(int* __restrict__ hist,
                                                       int* __restrict__ btot, int nblk) {
    __shared__ int s[512];
    int b = blockIdx.x;
    int tid = threadIdx.x;
    int v = (tid < nblk) ? hist[tid * NB + b] : 0;
    s[tid] = v;
    __syncthreads();
    for (int off = 1; off < 512; off <<= 1) {
        int t = (tid >= off) ? s[tid - off] : 0;
        __syncthreads();
        s[tid] += t;
        __syncthreads();
    }
    if (tid < nblk) hist[tid * NB + b] = s[tid] - v;   // exclusive
    if (tid == 511) btot[b] = s[511];
}

__global__ __launch_bounds__(NB) void scan_btot_kernel(const int* __restrict__ btot,
                                                       int* __restrict__ bstart) {
    __shared__ int s[NB];
    int tid = threadIdx.x;
    int v = btot[tid];
    s[tid] = v;
    __syncthreads();
    for (int off = 1; off < NB; off <<= 1) {
        int t = (tid >= off) ? s[tid - off] : 0;
        __syncthreads();
        s[tid] += t;
        __syncthreads();
    }
    bstart[tid] = s[tid] - v;
    if (tid == NB - 1) bstart[NB] = s[NB - 1];
}

__global__ __launch_bounds__(256) void bin_kernel(const void* __restrict__ ei,
                                                  const int* __restrict__ flag,
                                                  const int* __restrict__ hist,
                                                  const int* __restrict__ bstart,
                                                  int2* __restrict__ binned, int e, int shift) {
    __shared__ int c[NB];
    c[threadIdx.x] = 0;
    __syncthreads();
    int is64 = (*flag == 0);
    int base = blockIdx.x * BCHUNK;
    #pragma unroll
    for (int k = 0; k < BCHUNK / 256; ++k) {
        int i = base + k * 256 + threadIdx.x;
        if (i < e) {
            int sN = edge_at(ei, i, is64);
            int d  = edge_at(ei, e + i, is64);
            int b  = d >> shift;
            int r  = atomicAdd(&c[b], 1);
            int pos = bstart[b] + hist[blockIdx.x * NB + b] + r;
            binned[pos] = make_int2(sN, d);
        }
    }
}

// ---------------- CSR build pass B: bucket-owned count + scatter ----------------
__global__ __launch_bounds__(256) void count_binned_kernel(const int2* __restrict__ binned,
                                                           const int* __restrict__ bstart,
                                                           int* __restrict__ cnt) {
    int b = blockIdx.x;
    int beg = bstart[b], end = bstart[b + 1];
    for (int i = beg + threadIdx.x; i < end; i += 256)
        atomicAdd(&cnt[binned[i].y], 1);
}

__global__ __launch_bounds__(256) void scatter2_kernel(const int2* __restrict__ binned,
                                                       const int* __restrict__ bstart,
                                                       const int* __restrict__ rs,
                                                       int* __restrict__ cursor,
                                                       int* __restrict__ csr) {
    int b = blockIdx.x;
    int beg = bstart[b], end = bstart[b + 1];
    for (int i = beg + threadIdx.x; i < end; i += 256) {
        int2 p = binned[i];
        int pos = rs[p.y] + atomicAdd(&cursor[p.y], 1);
        csr[pos] = p.x;
    }
}

// ---------------- multi-block exclusive scan over cnt -> rs ----------------
__global__ __launch_bounds__(256) void scan_pass1(const int* __restrict__ cnt,
                                                  int* __restrict__ bsum, int n) {
    __shared__ int s[256];
    int i = blockIdx.x * 256 + threadIdx.x;
    s[threadIdx.x] = (i < n) ? cnt[i] : 0;
    __syncthreads();
    #pragma unroll
    for (int off = 128; off > 0; off >>= 1) {
        if (threadIdx.x < off) s[threadIdx.x] += s[threadIdx.x + off];
        __syncthreads();
    }
    if (threadIdx.x == 0) bsum[blockIdx.x] = s[0];
}

__global__ __launch_bounds__(1024) void scan_pass2(int* __restrict__ bsum, int nb) {
    __shared__ int s[1024];
    int tid = threadIdx.x;
    int v = (tid < nb) ? bsum[tid] : 0;
    s[tid] = v;
    __syncthreads();
    for (int off = 1; off < 1024; off <<= 1) {
        int t = (tid >= off) ? s[tid - off] : 0;
        __syncthreads();
        s[tid] += t;
        __syncthreads();
    }
    if (tid < nb) bsum[tid] = s[tid] - v;   // exclusive
}

__global__ __launch_bounds__(256) void scan_pass3(const int* __restrict__ cnt,
                                                  const int* __restrict__ bsum,
                                                  int* __restrict__ rs,
                                                  float* __restrict__ dis, int n, int e) {
    __shared__ int s[256];
    int i = blockIdx.x * 256 + threadIdx.x;
    int v = (i < n) ? cnt[i] : 0;
    s[threadIdx.x] = v;
    __syncthreads();
    #pragma unroll
    for (int off = 1; off < 256; off <<= 1) {
        int t = (threadIdx.x >= off) ? s[threadIdx.x - off] : 0;
        __syncthreads();
        s[threadIdx.x] += t;
        __syncthreads();
    }
    if (i < n) {
        rs[i] = s[threadIdx.x] - v + bsum[blockIdx.x];
        dis[i] = rsqrtf((float)v + 1.0f);
        if (i == n - 1) rs[n] = e;
    }
}

// ---------------- W split+transpose: W[k][c] fp32 -> WhT/WlT[c][k] bf16 ----------------
__global__ void wsplit_kernel(const float* __restrict__ W, unsigned short* __restrict__ WhT,
                              unsigned short* __restrict__ WlT) {
    int idx = blockIdx.x * 256 + threadIdx.x;   // 0..16383
    int k = idx >> 7, c = idx & 127;
    float w = W[idx];
    unsigned int u = __float_as_uint(w);
    unsigned short hi = (unsigned short)(u >> 16);
    float rem = w - __uint_as_float((unsigned int)hi << 16);
    unsigned short lo = (unsigned short)(__float_as_uint(rem) >> 16);
    WhT[c * 128 + k] = hi;
    WlT[c * 128 + k] = lo;
}

// ---------------- split-bf16 MFMA GEMM ----------------
__device__ __forceinline__ void split8(float4 a0, float4 a1, s16x8& h, s16x8& l) {
    float v[8] = {a0.x, a0.y, a0.z, a0.w, a1.x, a1.y, a1.z, a1.w};
    #pragma unroll
    for (int j = 0; j < 8; ++j) {
        unsigned int u = __float_as_uint(v[j]);
        unsigned short hi = (unsigned short)(u >> 16);
        float rem = v[j] - __uint_as_float((unsigned int)hi << 16);
        h[j] = (short)hi;
        l[j] = (short)(__float_as_uint(rem) >> 16);
    }
}

__global__ __launch_bounds__(256) void gemm_mfma_kernel(
    const float* __restrict__ X, const unsigned short* __restrict__ WhT,
    const unsigned short* __restrict__ WlT, const float* __restrict__ dis,
    float* __restrict__ out, int n) {
    __shared__ unsigned short bsh[128 * 128];   // [col][k] bf16 hi, swizzled
    __shared__ unsigned short bsl[128 * 128];   // [col][k] bf16 lo, swizzled
    const int tid = threadIdx.x;

    #pragma unroll
    for (int it = 0; it < 8; ++it) {
        int idx = it * 256 + tid;
        int col = idx >> 4;
        int ch  = idx & 15;
        int byte = (col * 256 + ch * 16) ^ ((col & 7) << 4);
        *(uint4*)((char*)bsh + byte) = ((const uint4*)WhT)[idx];
        *(uint4*)((char*)bsl + byte) = ((const uint4*)WlT)[idx];
    }
    __syncthreads();

    const int lane = tid & 63;
    const int wv = tid >> 6;
    const int rbase = blockIdx.x * 128 + wv * 32;
    const int lr = lane & 15;
    const int lg = lane >> 4;

    f32x4 acc[2][8];
    #pragma unroll
    for (int rt = 0; rt < 2; ++rt)
        #pragma unroll
        for (int ct = 0; ct < 8; ++ct) acc[rt][ct] = (f32x4)0.f;

    #pragma unroll
    for (int kk = 0; kk < 4; ++kk) {
        const int k0 = kk * 32 + lg * 8;
        s16x8 bh[8], bl[8];
        #pragma unroll
        for (int ct = 0; ct < 8; ++ct) {
            int col = ct * 16 + lr;
            int byte = (col * 256 + k0 * 2) ^ ((col & 7) << 4);
            bh[ct] = *(const s16x8*)((const char*)bsh + byte);
            bl[ct] = *(const s16x8*)((const char*)bsl + byte);
        }
        #pragma unroll
        for (int rt = 0; rt < 2; ++rt) {
            int row = rbase + rt * 16 + lr;
            float4 a0 = make_float4(0.f, 0.f, 0.f, 0.f);
            float4 a1 = make_float4(0.f, 0.f, 0.f, 0.f);
            if (row < n) {
                a0 = *(const float4*)&X[(size_t)row * CH + k0];
                a1 = *(const float4*)&X[(size_t)row * CH + k0 + 4];
            }
            s16x8 ah, al;
            split8(a0, a1, ah, al);
            #pragma unroll
            for (int ct = 0; ct < 8; ++ct) {
                acc[rt][ct] = __builtin_amdgcn_mfma_f32_16x16x32_bf16(ah, bh[ct], acc[rt][ct], 0, 0, 0);
                acc[rt][ct] = __builtin_amdgcn_mfma_f32_16x16x32_bf16(al, bh[ct], acc[rt][ct], 0, 0, 0);
                acc[rt][ct] = __builtin_amdgcn_mfma_f32_16x16x32_bf16(ah, bl[ct], acc[rt][ct], 0, 0, 0);
            }
        }
    }

    #pragma unroll
    for (int rt = 0; rt < 2; ++rt) {
        #pragma unroll
        for (int reg = 0; reg < 4; ++reg) {
            int row = rbase + rt * 16 + lg * 4 + reg;
            if (row < n) {
                float d = dis[row];
                #pragma unroll
                for (int ct = 0; ct < 8; ++ct) {
                    int col = ct * 16 + lr;
                    out[(size_t)row * CH + col] = acc[rt][ct][reg] * d;
                }
            }
        }
    }
}

// ---------------- aggregation (128 ch): half-wave (32 lanes) per dst, float4/lane ----------------
// 2 dsts per wave, 8 per block; 4-deep unroll -> 8 row-gathers in flight per wave
__global__ __launch_bounds__(256) void agg128_kernel(
    const float* __restrict__ Hs, const int* __restrict__ rs, const int* __restrict__ csr,
    const float* __restrict__ dis, const float* __restrict__ bias,
    float* __restrict__ out, int n, int relu) {
    int dst = blockIdx.x * 8 + (threadIdx.x >> 5);
    if (dst >= n) return;
    int lane = threadIdx.x & 31;
    int c = lane * 4;
    float4 acc = *(const float4*)&Hs[(size_t)dst * CH + c];  // self term
    int beg = rs[dst], end = rs[dst + 1];
    int last = end - 1;
    for (int i = beg; i < end; i += 4) {
        int i1 = i + 1 <= last ? i + 1 : last;
        int i2 = i + 2 <= last ? i + 2 : last;
        int i3 = i + 3 <= last ? i + 3 : last;
        int s0 = csr[i], s1 = csr[i1], s2 = csr[i2], s3 = csr[i3];
        float4 v0 = *(const float4*)&Hs[(size_t)s0 * CH + c];
        float4 v1 = *(const float4*)&Hs[(size_t)s1 * CH + c];
        float4 v2 = *(const float4*)&Hs[(size_t)s2 * CH + c];
        float4 v3 = *(const float4*)&Hs[(size_t)s3 * CH + c];
        float m1 = (i + 1 < end) ? 1.f : 0.f;
        float m2 = (i + 2 < end) ? 1.f : 0.f;
        float m3 = (i + 3 < end) ? 1.f : 0.f;
        acc.x += v0.x + m1 * v1.x + (m2 * v2.x + m3 * v3.x);
        acc.y += v0.y + m1 * v1.y + (m2 * v2.y + m3 * v3.y);
        acc.z += v0.z + m1 * v1.z + (m2 * v2.z + m3 * v3.z);
        acc.w += v0.w + m1 * v1.w + (m2 * v2.w + m3 * v3.w);
    }
    float d = dis[dst];
    float4 b = *(const float4*)&bias[c];
    float4 o;
    o.x = fmaf(acc.x, d, b.x);
    o.y = fmaf(acc.y, d, b.y);
    o.z = fmaf(acc.z, d, b.z);
    o.w = fmaf(acc.w, d, b.w);
    if (relu) {
        o.x = fmaxf(o.x, 0.f); o.y = fmaxf(o.y, 0.f);
        o.z = fmaxf(o.z, 0.f); o.w = fmaxf(o.w, 0.f);
    }
    *(float4*)&out[(size_t)dst * CH + c] = o;
}

// ---------------- layer 3 transform (128 -> 2): wave per row ----------------
__global__ __launch_bounds__(256) void gemm_out_kernel(
    const float* __restrict__ H, const float* __restrict__ W3,
    const float* __restrict__ dis, float* __restrict__ H3, int n) {
    int row = blockIdx.x * 4 + (threadIdx.x >> 6);
    int lane = threadIdx.x & 63;
    if (row >= n) return;
    float2 v = *(const float2*)&H[(size_t)row * CH + lane * 2];
    float4 w = *(const float4*)&W3[lane * 4];
    float a0 = v.x * w.x + v.y * w.z;
    float a1 = v.x * w.y + v.y * w.w;
    #pragma unroll
    for (int off = 32; off > 0; off >>= 1) {
        a0 += __shfl_xor(a0, off, 64);
        a1 += __shfl_xor(a1, off, 64);
    }
    if (lane == 0) {
        float d = dis[row];
        H3[row * 2]     = a0 * d;
        H3[row * 2 + 1] = a1 * d;
    }
}

// ---------------- layer 3 aggregation (2 ch): thread per dst, 4-deep ----------------
__global__ void agg_out_kernel(const float* __restrict__ H3, const int* __restrict__ rs,
                               const int* __restrict__ csr, const float* __restrict__ dis,
                               const float* __restrict__ b3, float* __restrict__ out, int n) {
    int dst = blockIdx.x * blockDim.x + threadIdx.x;
    if (dst >= n) return;
    float2 acc = *(const float2*)&H3[dst * 2];
    int beg = rs[dst], end = rs[dst + 1];
    int last = end - 1;
    for (int i = beg; i < end; i += 4) {
        int i1 = i + 1 <= last ? i + 1 : last;
        int i2 = i + 2 <= last ? i + 2 : last;
        int i3 = i + 3 <= last ? i + 3 : last;
        int s0 = csr[i], s1 = csr[i1], s2 = csr[i2], s3 = csr[i3];
        float2 v0 = *(const float2*)&H3[s0 * 2];
        float2 v1 = *(const float2*)&H3[s1 * 2];
        float2 v2 = *(const float2*)&H3[s2 * 2];
        float2 v3 = *(const float2*)&H3[s3 * 2];
        float m1 = (i + 1 < end) ? 1.f : 0.f;
        float m2 = (i + 2 < end) ? 1.f : 0.f;
        float m3 = (i + 3 < end) ? 1.f : 0.f;
        acc.x += v0.x + m1 * v1.x + (m2 * v2.x + m3 * v3.x);
        acc.y += v0.y + m1 * v1.y + (m2 * v2.y + m3 * v3.y);
    }
    float d = dis[dst];
    out[dst * 2]     = fmaf(acc.x, d, b3[0]);
    out[dst * 2 + 1] = fmaf(acc.y, d, b3[1]);
}

extern "C" void kernel_launch(void* const* d_in, const int* in_sizes, int n_in,
                              void* d_out, int out_size, void* d_ws, size_t ws_size,
                              hipStream_t stream) {
    const float* x  = (const float*)d_in[0];
    const void*  ei = d_in[1];
    const float* W1 = (const float*)d_in[2];
    const float* b1 = (const float*)d_in[3];
    const float* W2 = (const float*)d_in[4];
    const float* b2 = (const float*)d_in[5];
    const float* W3 = (const float*)d_in[6];
    const float* b3 = (const float*)d_in[7];
    float* out = (float*)d_out;

    const int n = in_sizes[0] / CH;      // 100000
    const int e = in_sizes[1] / 2;       // 1600000

    char* w = (char*)d_ws;
    size_t off = 0;
    auto alloc = [&](size_t bytes) { char* p = w + off; off = (off + bytes + 255) & ~(size_t)255; return p; };
    float* bufA   = (float*)alloc((size_t)n * CH * 4);   // also aliases `binned` during CSR build
    float* bufB   = (float*)alloc((size_t)n * CH * 4);   // also aliases `hist` during CSR build
    int*   csr    = (int*)  alloc((size_t)e * 4);
    float* dis    = (float*)alloc((size_t)n * 4);
    int*   rs     = (int*)  alloc(((size_t)n + 1) * 4);
    float* H3     = (float*)alloc((size_t)n * 2 * 4);
    int*   bsum   = (int*)  alloc(1024 * 4);
    int*   btot   = (int*)  alloc(NB * 4);
    int*   bstart = (int*)  alloc((NB + 1) * 4);
    unsigned short* WhT = (unsigned short*)alloc(128 * 128 * 2);
    unsigned short* WlT = (unsigned short*)alloc(128 * 128 * 2);
    char* zbase   = w + off;
    int*   cnt    = (int*)  alloc((size_t)n * 4);
    int*   cursor = (int*)  alloc((size_t)n * 4);
    int*   flag   = (int*)  alloc(256);
    size_t zbytes = (size_t)((w + off) - zbase);

    int2* binned = (int2*)bufA;          // e*8 = 12.8MB <= 51.2MB
    int*  hist   = (int*)bufB;           // nblk*NB*4 ~ 400KB

    int shift = 0;
    while (((n - 1) >> shift) >= NB) ++shift;

    hipMemsetAsync(zbase, 0, zbytes, stream);

    detect_kernel<<<8, 1024, 0, stream>>>((const int*)ei, flag, 2 * e);

    // ---- CSR build pass A: bin edges by dst bucket ----
    const int nblk = (e + BCHUNK - 1) / BCHUNK;
    hist_kernel<<<nblk, NB, 0, stream>>>(ei, flag, hist, e, shift);
    scan_col_kernel<<<NB, 512, 0, stream>>>(hist, btot, nblk);
    scan_btot_kernel<<<1, NB, 0, stream>>>(btot, bstart);
    bin_kernel<<<nblk, NB, 0, stream>>>(ei, flag, hist, bstart, binned, e, shift);

    // ---- degrees + rs/dis ----
    count_binned_kernel<<<NB, 256, 0, stream>>>(binned, bstart, cnt);
    const int nb = (n + 255) / 256;
    scan_pass1<<<nb, 256, 0, stream>>>(cnt, bsum, n);
    scan_pass2<<<1, 1024, 0, stream>>>(bsum, nb);
    scan_pass3<<<nb, 256, 0, stream>>>(cnt, bsum, rs, dis, n, e);

    // ---- CSR build pass B: bucket-owned scatter ----
    scatter2_kernel<<<NB, 256, 0, stream>>>(binned, bstart, rs, cursor, csr);

    const int mfmaGrid = (n + 127) / 128;
    const int aggGrid  = (n + 7) / 8;

    // layer 1
    wsplit_kernel<<<64, 256, 0, stream>>>(W1, WhT, WlT);
    gemm_mfma_kernel<<<mfmaGrid, 256, 0, stream>>>(x, WhT, WlT, dis, bufA, n);
    agg128_kernel<<<aggGrid, 256, 0, stream>>>(bufA, rs, csr, dis, b1, bufB, n, 1);
    // layer 2
    wsplit_kernel<<<64, 256, 0, stream>>>(W2, WhT, WlT);
    gemm_mfma_kernel<<<mfmaGrid, 256, 0, stream>>>(bufB, WhT, WlT, dis, bufA, n);
    agg128_kernel<<<aggGrid, 256, 0, stream>>>(bufA, rs, csr, dis, b2, bufB, n, 1);
    // layer 3
    gemm_out_kernel<<<(n + 3) / 4, 256, 0, stream>>>(bufB, W3, dis, H3, n);
    agg_out_kernel<<<(n + 255) / 256, 256, 0, stream>>>(H3, rs, csr, dis, b3, out, n);
}

// Round 7
// 387.266 us; speedup vs baseline: 1.1366x; 1.1366x over previous
//
#include <hip/hip_runtime.h>

#define CH 128
#define BCHUNK 4096   // edges per binning block (16 per thread @ 256 thr)
#define NB 256        // max buckets
#define MAXW 2048     // max bucket width for LDS count/cursor (shift <= 11)

typedef float f32x4 __attribute__((ext_vector_type(4)));
typedef short s16x8 __attribute__((ext_vector_type(8)));

// ---------------- edge dtype detection (int32 vs int64) ----------------
__global__ void detect_kernel(const int* __restrict__ ei, int* __restrict__ flag, int nwords) {
    int i = blockIdx.x * blockDim.x + threadIdx.x;
    int w = 2 * i + 1;
    if (w < nwords) {
        if (ei[w] != 0) atomicOr(flag, 1);
    }
}

__device__ __forceinline__ int edge_at(const void* ei, int idx, int is64) {
    if (is64) return (int)((const long long*)ei)[idx];
    return ((const int*)ei)[idx];
}

// ---------------- CSR build pass A: histogram / scans / bin ----------------
__global__ __launch_bounds__(256) void hist_kernel(const void* __restrict__ ei,
                                                   const int* __restrict__ flag,
                                                   int* __restrict__ hist, int e, int shift) {
    __shared__ int h[NB];
    h[threadIdx.x] = 0;
    __syncthreads();
    int is64 = (*flag == 0);
    int base = blockIdx.x * BCHUNK;
    #pragma unroll
    for (int k = 0; k < BCHUNK / 256; ++k) {
        int i = base + k * 256 + threadIdx.x;
        if (i < e) {
            int d = edge_at(ei, e + i, is64);
            atomicAdd(&h[d >> shift], 1);
        }
    }
    __syncthreads();
    hist[blockIdx.x * NB + threadIdx.x] = h[threadIdx.x];
}

// per-bucket exclusive scan over blocks (column scan); also bucket totals
__global__ __launch_bounds__(512) void scan_col_kernel(int* __restrict__ hist,
                                                       int* __restrict__ btot, int nblk) {
    __shared__ int s[512];
    int b = blockIdx.x;
    int tid = threadIdx.x;
    int v = (tid < nblk) ? hist[tid * NB + b] : 0;
    s[tid] = v;
    __syncthreads();
    for (int off = 1; off < 512; off <<= 1) {
        int t = (tid >= off) ? s[tid - off] : 0;
        __syncthreads();
        s[tid] += t;
        __syncthreads();
    }
    if (tid < nblk) hist[tid * NB + b] = s[tid] - v;   // exclusive
    if (tid == 511) btot[b] = s[511];
}

__global__ __launch_bounds__(NB) void scan_btot_kernel(const int* __restrict__ btot,
                                                       int* __restrict__ bstart) {
    __shared__ int s[NB];
    int tid = threadIdx.x;
    int v = btot[tid];
    s[tid] = v;
    __syncthreads();
    for (int off = 1; off < NB; off <<= 1) {
        int t = (tid >= off) ? s[tid - off] : 0;
        __syncthreads();
        s[tid] += t;
        __syncthreads();
    }
    bstart[tid] = s[tid] - v;
    if (tid == NB - 1) bstart[NB] = s[NB - 1];
}

__global__ __launch_bounds__(256) void bin_kernel(const void* __restrict__ ei,
                                                  const int* __restrict__ flag,
                                                  const int* __restrict__ hist,
                                                  const int* __restrict__ bstart,
                                                  int2* __restrict__ binned, int e, int shift) {
    __shared__ int c[NB];
    c[threadIdx.x] = 0;
    __syncthreads();
    int is64 = (*flag == 0);
    int base = blockIdx.x * BCHUNK;
    #pragma unroll
    for (int k = 0; k < BCHUNK / 256; ++k) {
        int i = base + k * 256 + threadIdx.x;
        if (i < e) {
            int sN = edge_at(ei, i, is64);
            int d  = edge_at(ei, e + i, is64);
            int b  = d >> shift;
            int r  = atomicAdd(&c[b], 1);
            int pos = bstart[b] + hist[blockIdx.x * NB + b] + r;
            binned[pos] = make_int2(sN, d);
        }
    }
}

// ---------------- CSR build pass B: bucket-owned count + scatter (LDS-local atomics) ----------------
__global__ __launch_bounds__(256) void count_binned_kernel(const int2* __restrict__ binned,
                                                           const int* __restrict__ bstart,
                                                           int* __restrict__ cnt,
                                                           int shift, int n) {
    __shared__ int lc[MAXW];
    int b = blockIdx.x;
    int dbase = b << shift;
    int W = 1 << shift;
    for (int i = threadIdx.x; i < W; i += 256) lc[i] = 0;
    __syncthreads();
    int beg = bstart[b], end = bstart[b + 1];
    for (int i = beg + threadIdx.x; i < end; i += 256)
        atomicAdd(&lc[binned[i].y - dbase], 1);
    __syncthreads();
    for (int i = threadIdx.x; i < W; i += 256)
        if (dbase + i < n) cnt[dbase + i] = lc[i];
}

__global__ __launch_bounds__(256) void scatter2_kernel(const int2* __restrict__ binned,
                                                       const int* __restrict__ bstart,
                                                       const int* __restrict__ rs,
                                                       int* __restrict__ csr, int shift) {
    __shared__ int lcur[MAXW];
    int b = blockIdx.x;
    int dbase = b << shift;
    int W = 1 << shift;
    for (int i = threadIdx.x; i < W; i += 256) lcur[i] = 0;
    __syncthreads();
    int beg = bstart[b], end = bstart[b + 1];
    for (int i = beg + threadIdx.x; i < end; i += 256) {
        int2 p = binned[i];
        int pos = rs[p.y] + atomicAdd(&lcur[p.y - dbase], 1);
        csr[pos] = p.x;
    }
}

// ---------------- multi-block exclusive scan over cnt -> rs ----------------
__global__ __launch_bounds__(256) void scan_pass1(const int* __restrict__ cnt,
                                                  int* __restrict__ bsum, int n) {
    __shared__ int s[256];
    int i = blockIdx.x * 256 + threadIdx.x;
    s[threadIdx.x] = (i < n) ? cnt[i] : 0;
    __syncthreads();
    #pragma unroll
    for (int off = 128; off > 0; off >>= 1) {
        if (threadIdx.x < off) s[threadIdx.x] += s[threadIdx.x + off];
        __syncthreads();
    }
    if (threadIdx.x == 0) bsum[blockIdx.x] = s[0];
}

__global__ __launch_bounds__(1024) void scan_pass2(int* __restrict__ bsum, int nb) {
    __shared__ int s[1024];
    int tid = threadIdx.x;
    int v = (tid < nb) ? bsum[tid] : 0;
    s[tid] = v;
    __syncthreads();
    for (int off = 1; off < 1024; off <<= 1) {
        int t = (tid >= off) ? s[tid - off] : 0;
        __syncthreads();
        s[tid] += t;
        __syncthreads();
    }
    if (tid < nb) bsum[tid] = s[tid] - v;   // exclusive
}

__global__ __launch_bounds__(256) void scan_pass3(const int* __restrict__ cnt,
                                                  const int* __restrict__ bsum,
                                                  int* __restrict__ rs,
                                                  float* __restrict__ dis, int n, int e) {
    __shared__ int s[256];
    int i = blockIdx.x * 256 + threadIdx.x;
    int v = (i < n) ? cnt[i] : 0;
    s[threadIdx.x] = v;
    __syncthreads();
    #pragma unroll
    for (int off = 1; off < 256; off <<= 1) {
        int t = (threadIdx.x >= off) ? s[threadIdx.x - off] : 0;
        __syncthreads();
        s[threadIdx.x] += t;
        __syncthreads();
    }
    if (i < n) {
        rs[i] = s[threadIdx.x] - v + bsum[blockIdx.x];
        dis[i] = rsqrtf((float)v + 1.0f);
        if (i == n - 1) rs[n] = e;
    }
}

// ---------------- W split+transpose: W[k][c] fp32 -> WhT/WlT[c][k] bf16 ----------------
__global__ void wsplit_kernel(const float* __restrict__ W, unsigned short* __restrict__ WhT,
                              unsigned short* __restrict__ WlT) {
    int idx = blockIdx.x * 256 + threadIdx.x;   // 0..16383
    int k = idx >> 7, c = idx & 127;
    float w = W[idx];
    unsigned int u = __float_as_uint(w);
    unsigned short hi = (unsigned short)(u >> 16);
    float rem = w - __uint_as_float((unsigned int)hi << 16);
    unsigned short lo = (unsigned short)(__float_as_uint(rem) >> 16);
    WhT[c * 128 + k] = hi;
    WlT[c * 128 + k] = lo;
}

// ---------------- split-bf16 MFMA GEMM ----------------
__device__ __forceinline__ void split8(float4 a0, float4 a1, s16x8& h, s16x8& l) {
    float v[8] = {a0.x, a0.y, a0.z, a0.w, a1.x, a1.y, a1.z, a1.w};
    #pragma unroll
    for (int j = 0; j < 8; ++j) {
        unsigned int u = __float_as_uint(v[j]);
        unsigned short hi = (unsigned short)(u >> 16);
        float rem = v[j] - __uint_as_float((unsigned int)hi << 16);
        h[j] = (short)hi;
        l[j] = (short)(__float_as_uint(rem) >> 16);
    }
}

__global__ __launch_bounds__(256) void gemm_mfma_kernel(
    const float* __restrict__ X, const unsigned short* __restrict__ WhT,
    const unsigned short* __restrict__ WlT, const float* __restrict__ dis,
    float* __restrict__ out, int n) {
    __shared__ unsigned short bsh[128 * 128];   // [col][k] bf16 hi, swizzled
    __shared__ unsigned short bsl[128 * 128];   // [col][k] bf16 lo, swizzled
    const int tid = threadIdx.x;

    #pragma unroll
    for (int it = 0; it < 8; ++it) {
        int idx = it * 256 + tid;
        int col = idx >> 4;
        int ch  = idx & 15;
        int byte = (col * 256 + ch * 16) ^ ((col & 7) << 4);
        *(uint4*)((char*)bsh + byte) = ((const uint4*)WhT)[idx];
        *(uint4*)((char*)bsl + byte) = ((const uint4*)WlT)[idx];
    }
    __syncthreads();

    const int lane = tid & 63;
    const int wv = tid >> 6;
    const int rbase = blockIdx.x * 128 + wv * 32;
    const int lr = lane & 15;
    const int lg = lane >> 4;

    f32x4 acc[2][8];
    #pragma unroll
    for (int rt = 0; rt < 2; ++rt)
        #pragma unroll
        for (int ct = 0; ct < 8; ++ct) acc[rt][ct] = (f32x4)0.f;

    #pragma unroll
    for (int kk = 0; kk < 4; ++kk) {
        const int k0 = kk * 32 + lg * 8;
        s16x8 bh[8], bl[8];
        #pragma unroll
        for (int ct = 0; ct < 8; ++ct) {
            int col = ct * 16 + lr;
            int byte = (col * 256 + k0 * 2) ^ ((col & 7) << 4);
            bh[ct] = *(const s16x8*)((const char*)bsh + byte);
            bl[ct] = *(const s16x8*)((const char*)bsl + byte);
        }
        #pragma unroll
        for (int rt = 0; rt < 2; ++rt) {
            int row = rbase + rt * 16 + lr;
            float4 a0 = make_float4(0.f, 0.f, 0.f, 0.f);
            float4 a1 = make_float4(0.f, 0.f, 0.f, 0.f);
            if (row < n) {
                a0 = *(const float4*)&X[(size_t)row * CH + k0];
                a1 = *(const float4*)&X[(size_t)row * CH + k0 + 4];
            }
            s16x8 ah, al;
            split8(a0, a1, ah, al);
            #pragma unroll
            for (int ct = 0; ct < 8; ++ct) {
                acc[rt][ct] = __builtin_amdgcn_mfma_f32_16x16x32_bf16(ah, bh[ct], acc[rt][ct], 0, 0, 0);
                acc[rt][ct] = __builtin_amdgcn_mfma_f32_16x16x32_bf16(al, bh[ct], acc[rt][ct], 0, 0, 0);
                acc[rt][ct] = __builtin_amdgcn_mfma_f32_16x16x32_bf16(ah, bl[ct], acc[rt][ct], 0, 0, 0);
            }
        }
    }

    #pragma unroll
    for (int rt = 0; rt < 2; ++rt) {
        #pragma unroll
        for (int reg = 0; reg < 4; ++reg) {
            int row = rbase + rt * 16 + lg * 4 + reg;
            if (row < n) {
                float d = dis[row];
                #pragma unroll
                for (int ct = 0; ct < 8; ++ct) {
                    int col = ct * 16 + lr;
                    out[(size_t)row * CH + col] = acc[rt][ct][reg] * d;
                }
            }
        }
    }
}

// ---------------- aggregation (128 ch): wave per dst, float2/lane, 4-deep (R5 config) ----------------
__global__ __launch_bounds__(256) void agg128_kernel(
    const float* __restrict__ Hs, const int* __restrict__ rs, const int* __restrict__ csr,
    const float* __restrict__ dis, const float* __restrict__ bias,
    float* __restrict__ out, int n, int relu) {
    int dst = blockIdx.x * 4 + (threadIdx.x >> 6);
    if (dst >= n) return;
    int lane = threadIdx.x & 63;
    int c = lane * 2;
    float2 acc = *(const float2*)&Hs[(size_t)dst * CH + c];
    int beg = rs[dst], end = rs[dst + 1];
    int last = end - 1;
    for (int i = beg; i < end; i += 4) {
        int i1 = i + 1 <= last ? i + 1 : last;
        int i2 = i + 2 <= last ? i + 2 : last;
        int i3 = i + 3 <= last ? i + 3 : last;
        int s0 = csr[i], s1 = csr[i1], s2 = csr[i2], s3 = csr[i3];
        float2 v0 = *(const float2*)&Hs[(size_t)s0 * CH + c];
        float2 v1 = *(const float2*)&Hs[(size_t)s1 * CH + c];
        float2 v2 = *(const float2*)&Hs[(size_t)s2 * CH + c];
        float2 v3 = *(const float2*)&Hs[(size_t)s3 * CH + c];
        float m1 = (i + 1 < end) ? 1.f : 0.f;
        float m2 = (i + 2 < end) ? 1.f : 0.f;
        float m3 = (i + 3 < end) ? 1.f : 0.f;
        acc.x += v0.x + m1 * v1.x + (m2 * v2.x + m3 * v3.x);
        acc.y += v0.y + m1 * v1.y + (m2 * v2.y + m3 * v3.y);
    }
    float d = dis[dst];
    float2 b = *(const float2*)&bias[c];
    float o0 = fmaf(acc.x, d, b.x);
    float o1 = fmaf(acc.y, d, b.y);
    if (relu) { o0 = fmaxf(o0, 0.f); o1 = fmaxf(o1, 0.f); }
    *(float2*)&out[(size_t)dst * CH + c] = make_float2(o0, o1);
}

// ---------------- layer 3 transform (128 -> 2): wave per row ----------------
__global__ __launch_bounds__(256) void gemm_out_kernel(
    const float* __restrict__ H, const float* __restrict__ W3,
    const float* __restrict__ dis, float* __restrict__ H3, int n) {
    int row = blockIdx.x * 4 + (threadIdx.x >> 6);
    int lane = threadIdx.x & 63;
    if (row >= n) return;
    float2 v = *(const float2*)&H[(size_t)row * CH + lane * 2];
    float4 w = *(const float4*)&W3[lane * 4];
    float a0 = v.x * w.x + v.y * w.z;
    float a1 = v.x * w.y + v.y * w.w;
    #pragma unroll
    for (int off = 32; off > 0; off >>= 1) {
        a0 += __shfl_xor(a0, off, 64);
        a1 += __shfl_xor(a1, off, 64);
    }
    if (lane == 0) {
        float d = dis[row];
        H3[row * 2]     = a0 * d;
        H3[row * 2 + 1] = a1 * d;
    }
}

// ---------------- layer 3 aggregation (2 ch): thread per dst, 4-deep ----------------
__global__ void agg_out_kernel(const float* __restrict__ H3, const int* __restrict__ rs,
                               const int* __restrict__ csr, const float* __restrict__ dis,
                               const float* __restrict__ b3, float* __restrict__ out, int n) {
    int dst = blockIdx.x * blockDim.x + threadIdx.x;
    if (dst >= n) return;
    float2 acc = *(const float2*)&H3[dst * 2];
    int beg = rs[dst], end = rs[dst + 1];
    int last = end - 1;
    for (int i = beg; i < end; i += 4) {
        int i1 = i + 1 <= last ? i + 1 : last;
        int i2 = i + 2 <= last ? i + 2 : last;
        int i3 = i + 3 <= last ? i + 3 : last;
        int s0 = csr[i], s1 = csr[i1], s2 = csr[i2], s3 = csr[i3];
        float2 v0 = *(const float2*)&H3[s0 * 2];
        float2 v1 = *(const float2*)&H3[s1 * 2];
        float2 v2 = *(const float2*)&H3[s2 * 2];
        float2 v3 = *(const float2*)&H3[s3 * 2];
        float m1 = (i + 1 < end) ? 1.f : 0.f;
        float m2 = (i + 2 < end) ? 1.f : 0.f;
        float m3 = (i + 3 < end) ? 1.f : 0.f;
        acc.x += v0.x + m1 * v1.x + (m2 * v2.x + m3 * v3.x);
        acc.y += v0.y + m1 * v1.y + (m2 * v2.y + m3 * v3.y);
    }
    float d = dis[dst];
    out[dst * 2]     = fmaf(acc.x, d, b3[0]);
    out[dst * 2 + 1] = fmaf(acc.y, d, b3[1]);
}

extern "C" void kernel_launch(void* const* d_in, const int* in_sizes, int n_in,
                              void* d_out, int out_size, void* d_ws, size_t ws_size,
                              hipStream_t stream) {
    const float* x  = (const float*)d_in[0];
    const void*  ei = d_in[1];
    const float* W1 = (const float*)d_in[2];
    const float* b1 = (const float*)d_in[3];
    const float* W2 = (const float*)d_in[4];
    const float* b2 = (const float*)d_in[5];
    const float* W3 = (const float*)d_in[6];
    const float* b3 = (const float*)d_in[7];
    float* out = (float*)d_out;

    const int n = in_sizes[0] / CH;      // 100000
    const int e = in_sizes[1] / 2;       // 1600000

    char* w = (char*)d_ws;
    size_t off = 0;
    auto alloc = [&](size_t bytes) { char* p = w + off; off = (off + bytes + 255) & ~(size_t)255; return p; };
    float* bufA   = (float*)alloc((size_t)n * CH * 4);   // also aliases `binned` during CSR build
    float* bufB   = (float*)alloc((size_t)n * CH * 4);   // also aliases `hist` during CSR build
    int*   csr    = (int*)  alloc((size_t)e * 4);
    float* dis    = (float*)alloc((size_t)n * 4);
    int*   rs     = (int*)  alloc(((size_t)n + 1) * 4);
    float* H3     = (float*)alloc((size_t)n * 2 * 4);
    int*   bsum   = (int*)  alloc(1024 * 4);
    int*   btot   = (int*)  alloc(NB * 4);
    int*   bstart = (int*)  alloc((NB + 1) * 4);
    unsigned short* WhT = (unsigned short*)alloc(128 * 128 * 2);
    unsigned short* WlT = (unsigned short*)alloc(128 * 128 * 2);
    char* zbase   = w + off;
    int*   cnt    = (int*)  alloc((size_t)n * 4);
    int*   flag   = (int*)  alloc(256);
    size_t zbytes = (size_t)((w + off) - zbase);

    int2* binned = (int2*)bufA;          // e*8 = 12.8MB <= 51.2MB
    int*  hist   = (int*)bufB;           // nblk*NB*4 ~ 400KB

    // bucket shift: buckets of 2^shift dsts, <= NB buckets (LDS path needs shift <= 11)
    int shift = 0;
    while (((n - 1) >> shift) >= NB) ++shift;

    hipMemsetAsync(zbase, 0, zbytes, stream);

    detect_kernel<<<8, 1024, 0, stream>>>((const int*)ei, flag, 2 * e);

    // ---- CSR build pass A: bin edges by dst bucket ----
    const int nblk = (e + BCHUNK - 1) / BCHUNK;
    hist_kernel<<<nblk, NB, 0, stream>>>(ei, flag, hist, e, shift);
    scan_col_kernel<<<NB, 512, 0, stream>>>(hist, btot, nblk);
    scan_btot_kernel<<<1, NB, 0, stream>>>(btot, bstart);
    bin_kernel<<<nblk, NB, 0, stream>>>(ei, flag, hist, bstart, binned, e, shift);

    // ---- degrees + rs/dis (LDS-local per-bucket counting) ----
    count_binned_kernel<<<NB, 256, 0, stream>>>(binned, bstart, cnt, shift, n);
    const int nb = (n + 255) / 256;
    scan_pass1<<<nb, 256, 0, stream>>>(cnt, bsum, n);
    scan_pass2<<<1, 1024, 0, stream>>>(bsum, nb);
    scan_pass3<<<nb, 256, 0, stream>>>(cnt, bsum, rs, dis, n, e);

    // ---- CSR build pass B: bucket-owned scatter (LDS cursor) ----
    scatter2_kernel<<<NB, 256, 0, stream>>>(binned, bstart, rs, csr, shift);

    const int mfmaGrid = (n + 127) / 128;
    const int aggGrid  = (n + 3) / 4;

    // layer 1
    wsplit_kernel<<<64, 256, 0, stream>>>(W1, WhT, WlT);
    gemm_mfma_kernel<<<mfmaGrid, 256, 0, stream>>>(x, WhT, WlT, dis, bufA, n);
    agg128_kernel<<<aggGrid, 256, 0, stream>>>(bufA, rs, csr, dis, b1, bufB, n, 1);
    // layer 2
    wsplit_kernel<<<64, 256, 0, stream>>>(W2, WhT, WlT);
    gemm_mfma_kernel<<<mfmaGrid, 256, 0, stream>>>(bufB, WhT, WlT, dis, bufA, n);
    agg128_kernel<<<aggGrid, 256, 0, stream>>>(bufA, rs, csr, dis, b2, bufB, n, 1);
    // layer 3
    gemm_out_kernel<<<(n + 3) / 4, 256, 0, stream>>>(bufB, W3, dis, H3, n);
    agg_out_kernel<<<(n + 255) / 256, 256, 0, stream>>>(H3, rs, csr, dis, b3, out, n);
}

// Round 8
// 354.246 us; speedup vs baseline: 1.2426x; 1.0932x over previous
//
#include <hip/hip_runtime.h>

#define CH 128
#define BCHUNK 4096   // edges per binning block (16 per thread @ 256 thr)
#define NB 256        // max buckets
#define MAXW 2048     // max bucket width for LDS count/cursor (shift <= 11)

typedef float f32x4 __attribute__((ext_vector_type(4)));
typedef short s16x8 __attribute__((ext_vector_type(8)));

// ---------------- edge dtype detection (int32 vs int64), sampled ----------------
// int64 => odd 32-bit words all zero. Sample first 16384 words: P(false int32) ~ 0.
__global__ void detect_kernel(const int* __restrict__ ei, int* __restrict__ flag, int nwords) {
    int w = 2 * threadIdx.x + 1 + 2048 * blockIdx.x;
    if (w < nwords) {
        if (ei[w] != 0) atomicOr(flag, 1);
    }
}

__device__ __forceinline__ int edge_at(const void* ei, int idx, int is64) {
    if (is64) return (int)((const long long*)ei)[idx];
    return ((const int*)ei)[idx];
}

// ---------------- CSR build pass A: histogram / scans / bin ----------------
__global__ __launch_bounds__(256) void hist_kernel(const void* __restrict__ ei,
                                                   const int* __restrict__ flag,
                                                   int* __restrict__ hist, int e, int shift) {
    __shared__ int h[NB];
    h[threadIdx.x] = 0;
    __syncthreads();
    int is64 = (*flag == 0);
    int base = blockIdx.x * BCHUNK;
    #pragma unroll
    for (int k = 0; k < BCHUNK / 256; ++k) {
        int i = base + k * 256 + threadIdx.x;
        if (i < e) {
            int d = edge_at(ei, e + i, is64);
            atomicAdd(&h[d >> shift], 1);
        }
    }
    __syncthreads();
    hist[blockIdx.x * NB + threadIdx.x] = h[threadIdx.x];
}

// per-bucket exclusive scan over blocks (column scan); also bucket totals
__global__ __launch_bounds__(512) void scan_col_kernel(int* __restrict__ hist,
                                                       int* __restrict__ btot, int nblk) {
    __shared__ int s[512];
    int b = blockIdx.x;
    int tid = threadIdx.x;
    int v = (tid < nblk) ? hist[tid * NB + b] : 0;
    s[tid] = v;
    __syncthreads();
    for (int off = 1; off < 512; off <<= 1) {
        int t = (tid >= off) ? s[tid - off] : 0;
        __syncthreads();
        s[tid] += t;
        __syncthreads();
    }
    if (tid < nblk) hist[tid * NB + b] = s[tid] - v;   // exclusive
    if (tid == 511) btot[b] = s[511];
}

__global__ __launch_bounds__(NB) void scan_btot_kernel(const int* __restrict__ btot,
                                                       int* __restrict__ bstart) {
    __shared__ int s[NB];
    int tid = threadIdx.x;
    int v = btot[tid];
    s[tid] = v;
    __syncthreads();
    for (int off = 1; off < NB; off <<= 1) {
        int t = (tid >= off) ? s[tid - off] : 0;
        __syncthreads();
        s[tid] += t;
        __syncthreads();
    }
    bstart[tid] = s[tid] - v;
    if (tid == NB - 1) bstart[NB] = s[NB - 1];
}

__global__ __launch_bounds__(256) void bin_kernel(const void* __restrict__ ei,
                                                  const int* __restrict__ flag,
                                                  const int* __restrict__ hist,
                                                  const int* __restrict__ bstart,
                                                  int2* __restrict__ binned, int e, int shift) {
    __shared__ int c[NB];
    c[threadIdx.x] = 0;
    __syncthreads();
    int is64 = (*flag == 0);
    int base = blockIdx.x * BCHUNK;
    #pragma unroll
    for (int k = 0; k < BCHUNK / 256; ++k) {
        int i = base + k * 256 + threadIdx.x;
        if (i < e) {
            int sN = edge_at(ei, i, is64);
            int d  = edge_at(ei, e + i, is64);
            int b  = d >> shift;
            int r  = atomicAdd(&c[b], 1);
            int pos = bstart[b] + hist[blockIdx.x * NB + b] + r;
            binned[pos] = make_int2(sN, d);
        }
    }
}

// ---------------- CSR finalize: per-bucket count + scan + rs/dis + scatter, all in LDS ----------------
// rs[d] = bstart[b] + local_prefix(d) because csr is bucket-major and dst-ordered within bucket.
__global__ __launch_bounds__(256) void finalize_bucket_kernel(
    const int2* __restrict__ binned, const int* __restrict__ bstart,
    int* __restrict__ rs, float* __restrict__ dis, int* __restrict__ csr,
    int shift, int n, int e) {
    __shared__ int lc[MAXW];
    __shared__ int ps[256];
    int b = blockIdx.x;
    int tid = threadIdx.x;
    int dbase = b << shift;
    int W = 1 << shift;
    for (int i = tid; i < W; i += 256) lc[i] = 0;
    __syncthreads();
    int beg = bstart[b], end = bstart[b + 1];
    for (int i = beg + tid; i < end; i += 256)
        atomicAdd(&lc[binned[i].y - dbase], 1);
    __syncthreads();
    // exclusive scan of lc[0..W): per-thread chunk serial + block scan of partials
    int chunk = (W + 255) >> 8;
    int s0 = tid * chunk;
    int sum = 0;
    for (int j = 0; j < chunk; ++j) {
        int idx = s0 + j;
        if (idx < W) sum += lc[idx];
    }
    ps[tid] = sum;
    __syncthreads();
    for (int off = 1; off < 256; off <<= 1) {
        int t = (tid >= off) ? ps[tid - off] : 0;
        __syncthreads();
        ps[tid] += t;
        __syncthreads();
    }
    int pref = (tid == 0) ? 0 : ps[tid - 1];
    for (int j = 0; j < chunk; ++j) {
        int idx = s0 + j;
        if (idx < W) {
            int c = lc[idx];
            if (dbase + idx < n) {
                rs[dbase + idx] = beg + pref;
                dis[dbase + idx] = rsqrtf((float)c + 1.0f);
            }
            lc[idx] = pref;          // becomes bucket-local cursor
            pref += c;
        }
    }
    if (b == 0 && tid == 0) rs[n] = e;
    __syncthreads();
    // scatter
    for (int i = beg + tid; i < end; i += 256) {
        int2 p = binned[i];
        int pos = beg + atomicAdd(&lc[p.y - dbase], 1);
        csr[pos] = p.x;
    }
}

// ---------------- W split+transpose (both layers in one launch) ----------------
__global__ void wsplit_kernel(const float* __restrict__ W1, const float* __restrict__ W2,
                              unsigned short* __restrict__ WhT1, unsigned short* __restrict__ WlT1,
                              unsigned short* __restrict__ WhT2, unsigned short* __restrict__ WlT2) {
    int g = blockIdx.x * 256 + threadIdx.x;      // 0..32767
    const float* W = (g < 16384) ? W1 : W2;
    unsigned short* WhT = (g < 16384) ? WhT1 : WhT2;
    unsigned short* WlT = (g < 16384) ? WlT1 : WlT2;
    int idx = g & 16383;
    int k = idx >> 7, c = idx & 127;
    float w = W[idx];
    unsigned int u = __float_as_uint(w);
    unsigned short hi = (unsigned short)(u >> 16);
    float rem = w - __uint_as_float((unsigned int)hi << 16);
    unsigned short lo = (unsigned short)(__float_as_uint(rem) >> 16);
    WhT[c * 128 + k] = hi;
    WlT[c * 128 + k] = lo;
}

// ---------------- split-bf16 MFMA GEMM ----------------
__device__ __forceinline__ void split8(float4 a0, float4 a1, s16x8& h, s16x8& l) {
    float v[8] = {a0.x, a0.y, a0.z, a0.w, a1.x, a1.y, a1.z, a1.w};
    #pragma unroll
    for (int j = 0; j < 8; ++j) {
        unsigned int u = __float_as_uint(v[j]);
        unsigned short hi = (unsigned short)(u >> 16);
        float rem = v[j] - __uint_as_float((unsigned int)hi << 16);
        h[j] = (short)hi;
        l[j] = (short)(__float_as_uint(rem) >> 16);
    }
}

__global__ __launch_bounds__(256) void gemm_mfma_kernel(
    const float* __restrict__ X, const unsigned short* __restrict__ WhT,
    const unsigned short* __restrict__ WlT, const float* __restrict__ dis,
    float* __restrict__ out, int n) {
    __shared__ unsigned short bsh[128 * 128];   // [col][k] bf16 hi, swizzled
    __shared__ unsigned short bsl[128 * 128];   // [col][k] bf16 lo, swizzled
    const int tid = threadIdx.x;

    #pragma unroll
    for (int it = 0; it < 8; ++it) {
        int idx = it * 256 + tid;
        int col = idx >> 4;
        int ch  = idx & 15;
        int byte = (col * 256 + ch * 16) ^ ((col & 7) << 4);
        *(uint4*)((char*)bsh + byte) = ((const uint4*)WhT)[idx];
        *(uint4*)((char*)bsl + byte) = ((const uint4*)WlT)[idx];
    }
    __syncthreads();

    const int lane = tid & 63;
    const int wv = tid >> 6;
    const int rbase = blockIdx.x * 128 + wv * 32;
    const int lr = lane & 15;
    const int lg = lane >> 4;

    f32x4 acc[2][8];
    #pragma unroll
    for (int rt = 0; rt < 2; ++rt)
        #pragma unroll
        for (int ct = 0; ct < 8; ++ct) acc[rt][ct] = (f32x4)0.f;

    #pragma unroll
    for (int kk = 0; kk < 4; ++kk) {
        const int k0 = kk * 32 + lg * 8;
        s16x8 bh[8], bl[8];
        #pragma unroll
        for (int ct = 0; ct < 8; ++ct) {
            int col = ct * 16 + lr;
            int byte = (col * 256 + k0 * 2) ^ ((col & 7) << 4);
            bh[ct] = *(const s16x8*)((const char*)bsh + byte);
            bl[ct] = *(const s16x8*)((const char*)bsl + byte);
        }
        #pragma unroll
        for (int rt = 0; rt < 2; ++rt) {
            int row = rbase + rt * 16 + lr;
            float4 a0 = make_float4(0.f, 0.f, 0.f, 0.f);
            float4 a1 = make_float4(0.f, 0.f, 0.f, 0.f);
            if (row < n) {
                a0 = *(const float4*)&X[(size_t)row * CH + k0];
                a1 = *(const float4*)&X[(size_t)row * CH + k0 + 4];
            }
            s16x8 ah, al;
            split8(a0, a1, ah, al);
            #pragma unroll
            for (int ct = 0; ct < 8; ++ct) {
                acc[rt][ct] = __builtin_amdgcn_mfma_f32_16x16x32_bf16(ah, bh[ct], acc[rt][ct], 0, 0, 0);
                acc[rt][ct] = __builtin_amdgcn_mfma_f32_16x16x32_bf16(al, bh[ct], acc[rt][ct], 0, 0, 0);
                acc[rt][ct] = __builtin_amdgcn_mfma_f32_16x16x32_bf16(ah, bl[ct], acc[rt][ct], 0, 0, 0);
            }
        }
    }

    #pragma unroll
    for (int rt = 0; rt < 2; ++rt) {
        #pragma unroll
        for (int reg = 0; reg < 4; ++reg) {
            int row = rbase + rt * 16 + lg * 4 + reg;
            if (row < n) {
                float d = dis[row];
                #pragma unroll
                for (int ct = 0; ct < 8; ++ct) {
                    int col = ct * 16 + lr;
                    out[(size_t)row * CH + col] = acc[rt][ct][reg] * d;
                }
            }
        }
    }
}

// ---------------- aggregation (128 ch): wave per dst, float2/lane, 4-deep ----------------
// Mode A (W3c == null): out[dst][:] = relu(dis*sum + bias)
// Mode B (W3c != null): fused layer-3 transform; writes H3[dst][0:2] only (skips 51MB out write)
__global__ __launch_bounds__(256) void agg128_kernel(
    const float* __restrict__ Hs, const int* __restrict__ rs, const int* __restrict__ csr,
    const float* __restrict__ dis, const float* __restrict__ bias,
    float* __restrict__ out, int n,
    const float* __restrict__ W3c, float* __restrict__ H3) {
    int dst = blockIdx.x * 4 + (threadIdx.x >> 6);
    if (dst >= n) return;
    int lane = threadIdx.x & 63;
    int c = lane * 2;
    float2 acc = *(const float2*)&Hs[(size_t)dst * CH + c];
    int beg = rs[dst], end = rs[dst + 1];
    int last = end - 1;
    for (int i = beg; i < end; i += 4) {
        int i1 = i + 1 <= last ? i + 1 : last;
        int i2 = i + 2 <= last ? i + 2 : last;
        int i3 = i + 3 <= last ? i + 3 : last;
        int s0 = csr[i], s1 = csr[i1], s2 = csr[i2], s3 = csr[i3];
        float2 v0 = *(const float2*)&Hs[(size_t)s0 * CH + c];
        float2 v1 = *(const float2*)&Hs[(size_t)s1 * CH + c];
        float2 v2 = *(const float2*)&Hs[(size_t)s2 * CH + c];
        float2 v3 = *(const float2*)&Hs[(size_t)s3 * CH + c];
        float m1 = (i + 1 < end) ? 1.f : 0.f;
        float m2 = (i + 2 < end) ? 1.f : 0.f;
        float m3 = (i + 3 < end) ? 1.f : 0.f;
        acc.x += v0.x + m1 * v1.x + (m2 * v2.x + m3 * v3.x);
        acc.y += v0.y + m1 * v1.y + (m2 * v2.y + m3 * v3.y);
    }
    float d = dis[dst];
    float2 b = *(const float2*)&bias[c];
    float o0 = fmaxf(fmaf(acc.x, d, b.x), 0.f);
    float o1 = fmaxf(fmaf(acc.y, d, b.y), 0.f);
    if (W3c == nullptr) {
        *(float2*)&out[(size_t)dst * CH + c] = make_float2(o0, o1);
    } else {
        // fused layer-3 transform: H3[dst] = dis[dst] * (h2[dst] . W3)
        float4 w4 = *(const float4*)&W3c[lane * 4];
        float a0 = o0 * w4.x + o1 * w4.z;
        float a1 = o0 * w4.y + o1 * w4.w;
        #pragma unroll
        for (int off = 32; off > 0; off >>= 1) {
            a0 += __shfl_xor(a0, off, 64);
            a1 += __shfl_xor(a1, off, 64);
        }
        if (lane == 0) {
            H3[dst * 2]     = a0 * d;
            H3[dst * 2 + 1] = a1 * d;
        }
    }
}

// ---------------- layer 3 aggregation (2 ch): thread per dst, 4-deep ----------------
__global__ void agg_out_kernel(const float* __restrict__ H3, const int* __restrict__ rs,
                               const int* __restrict__ csr, const float* __restrict__ dis,
                               const float* __restrict__ b3, float* __restrict__ out, int n) {
    int dst = blockIdx.x * blockDim.x + threadIdx.x;
    if (dst >= n) return;
    float2 acc = *(const float2*)&H3[dst * 2];
    int beg = rs[dst], end = rs[dst + 1];
    int last = end - 1;
    for (int i = beg; i < end; i += 4) {
        int i1 = i + 1 <= last ? i + 1 : last;
        int i2 = i + 2 <= last ? i + 2 : last;
        int i3 = i + 3 <= last ? i + 3 : last;
        int s0 = csr[i], s1 = csr[i1], s2 = csr[i2], s3 = csr[i3];
        float2 v0 = *(const float2*)&H3[s0 * 2];
        float2 v1 = *(const float2*)&H3[s1 * 2];
        float2 v2 = *(const float2*)&H3[s2 * 2];
        float2 v3 = *(const float2*)&H3[s3 * 2];
        float m1 = (i + 1 < end) ? 1.f : 0.f;
        float m2 = (i + 2 < end) ? 1.f : 0.f;
        float m3 = (i + 3 < end) ? 1.f : 0.f;
        acc.x += v0.x + m1 * v1.x + (m2 * v2.x + m3 * v3.x);
        acc.y += v0.y + m1 * v1.y + (m2 * v2.y + m3 * v3.y);
    }
    float d = dis[dst];
    out[dst * 2]     = fmaf(acc.x, d, b3[0]);
    out[dst * 2 + 1] = fmaf(acc.y, d, b3[1]);
}

extern "C" void kernel_launch(void* const* d_in, const int* in_sizes, int n_in,
                              void* d_out, int out_size, void* d_ws, size_t ws_size,
                              hipStream_t stream) {
    const float* x  = (const float*)d_in[0];
    const void*  ei = d_in[1];
    const float* W1 = (const float*)d_in[2];
    const float* b1 = (const float*)d_in[3];
    const float* W2 = (const float*)d_in[4];
    const float* b2 = (const float*)d_in[5];
    const float* W3 = (const float*)d_in[6];
    const float* b3 = (const float*)d_in[7];
    float* out = (float*)d_out;

    const int n = in_sizes[0] / CH;      // 100000
    const int e = in_sizes[1] / 2;       // 1600000

    char* w = (char*)d_ws;
    size_t off = 0;
    auto alloc = [&](size_t bytes) { char* p = w + off; off = (off + bytes + 255) & ~(size_t)255; return p; };
    float* bufA   = (float*)alloc((size_t)n * CH * 4);   // aliases `binned` during CSR build
    float* bufB   = (float*)alloc((size_t)n * CH * 4);   // aliases `hist` during CSR build
    int*   csr    = (int*)  alloc((size_t)e * 4);
    float* dis    = (float*)alloc((size_t)n * 4);
    int*   rs     = (int*)  alloc(((size_t)n + 1) * 4);
    float* H3     = (float*)alloc((size_t)n * 2 * 4);
    int*   btot   = (int*)  alloc(NB * 4);
    int*   bstart = (int*)  alloc((NB + 1) * 4);
    unsigned short* WhT1 = (unsigned short*)alloc(128 * 128 * 2);
    unsigned short* WlT1 = (unsigned short*)alloc(128 * 128 * 2);
    unsigned short* WhT2 = (unsigned short*)alloc(128 * 128 * 2);
    unsigned short* WlT2 = (unsigned short*)alloc(128 * 128 * 2);
    char* zbase   = w + off;
    int*   flag   = (int*)  alloc(256);
    size_t zbytes = (size_t)((w + off) - zbase);

    int2* binned = (int2*)bufA;          // e*8 = 12.8MB <= 51.2MB
    int*  hist   = (int*)bufB;           // nblk*NB*4 ~ 400KB

    // bucket shift: buckets of 2^shift dsts, <= NB buckets (LDS path needs shift <= 11)
    int shift = 0;
    while (((n - 1) >> shift) >= NB) ++shift;

    hipMemsetAsync(zbase, 0, zbytes, stream);

    // sampled dtype detection (first 16K words)
    int nwords = 2 * e < 16384 ? 2 * e : 16384;
    detect_kernel<<<8, 1024, 0, stream>>>((const int*)ei, flag, nwords);

    // split both weight matrices upfront
    wsplit_kernel<<<128, 256, 0, stream>>>(W1, W2, WhT1, WlT1, WhT2, WlT2);

    // ---- CSR build: bin by dst bucket, then per-bucket finalize ----
    const int nblk = (e + BCHUNK - 1) / BCHUNK;
    hist_kernel<<<nblk, NB, 0, stream>>>(ei, flag, hist, e, shift);
    scan_col_kernel<<<NB, 512, 0, stream>>>(hist, btot, nblk);
    scan_btot_kernel<<<1, NB, 0, stream>>>(btot, bstart);
    bin_kernel<<<nblk, NB, 0, stream>>>(ei, flag, hist, bstart, binned, e, shift);
    finalize_bucket_kernel<<<NB, 256, 0, stream>>>(binned, bstart, rs, dis, csr, shift, n, e);

    const int mfmaGrid = (n + 127) / 128;
    const int aggGrid  = (n + 3) / 4;

    // layer 1
    gemm_mfma_kernel<<<mfmaGrid, 256, 0, stream>>>(x, WhT1, WlT1, dis, bufA, n);
    agg128_kernel<<<aggGrid, 256, 0, stream>>>(bufA, rs, csr, dis, b1, bufB, n, nullptr, nullptr);
    // layer 2 (+ fused layer-3 transform in agg epilogue)
    gemm_mfma_kernel<<<mfmaGrid, 256, 0, stream>>>(bufB, WhT2, WlT2, dis, bufA, n);
    agg128_kernel<<<aggGrid, 256, 0, stream>>>(bufA, rs, csr, dis, b2, nullptr, n, W3, H3);
    // layer 3 aggregation
    agg_out_kernel<<<(n + 255) / 256, 256, 0, stream>>>(H3, rs, csr, dis, b3, out, n);
}

// Round 9
// 265.610 us; speedup vs baseline: 1.6573x; 1.3337x over previous
//
#include <hip/hip_runtime.h>

#define CH 128
#define BCHUNK 4096   // edges per binning block (16 per thread @ 256 thr)
#define NB 256        // max buckets
#define MAXW 2048     // max bucket width for LDS count/cursor (shift <= 11)

typedef float f32x4 __attribute__((ext_vector_type(4)));
typedef short s16x8 __attribute__((ext_vector_type(8)));
typedef _Float16 f16;
typedef _Float16 f16x2 __attribute__((ext_vector_type(2)));

// ---------------- edge dtype detection (int32 vs int64), sampled ----------------
__global__ void detect_kernel(const int* __restrict__ ei, int* __restrict__ flag, int nwords) {
    int w = 2 * threadIdx.x + 1 + 2048 * blockIdx.x;
    if (w < nwords) {
        if (ei[w] != 0) atomicOr(flag, 1);
    }
}

__device__ __forceinline__ int edge_at(const void* ei, int idx, int is64) {
    if (is64) return (int)((const long long*)ei)[idx];
    return ((const int*)ei)[idx];
}

// ---------------- CSR build pass A: histogram / scans / bin ----------------
__global__ __launch_bounds__(256) void hist_kernel(const void* __restrict__ ei,
                                                   const int* __restrict__ flag,
                                                   int* __restrict__ hist, int e, int shift) {
    __shared__ int h[NB];
    h[threadIdx.x] = 0;
    __syncthreads();
    int is64 = (*flag == 0);
    int base = blockIdx.x * BCHUNK;
    #pragma unroll
    for (int k = 0; k < BCHUNK / 256; ++k) {
        int i = base + k * 256 + threadIdx.x;
        if (i < e) {
            int d = edge_at(ei, e + i, is64);
            atomicAdd(&h[d >> shift], 1);
        }
    }
    __syncthreads();
    hist[blockIdx.x * NB + threadIdx.x] = h[threadIdx.x];
}

__global__ __launch_bounds__(512) void scan_col_kernel(int* __restrict__ hist,
                                                       int* __restrict__ btot, int nblk) {
    __shared__ int s[512];
    int b = blockIdx.x;
    int tid = threadIdx.x;
    int v = (tid < nblk) ? hist[tid * NB + b] : 0;
    s[tid] = v;
    __syncthreads();
    for (int off = 1; off < 512; off <<= 1) {
        int t = (tid >= off) ? s[tid - off] : 0;
        __syncthreads();
        s[tid] += t;
        __syncthreads();
    }
    if (tid < nblk) hist[tid * NB + b] = s[tid] - v;   // exclusive
    if (tid == 511) btot[b] = s[511];
}

__global__ __launch_bounds__(NB) void scan_btot_kernel(const int* __restrict__ btot,
                                                       int* __restrict__ bstart) {
    __shared__ int s[NB];
    int tid = threadIdx.x;
    int v = btot[tid];
    s[tid] = v;
    __syncthreads();
    for (int off = 1; off < NB; off <<= 1) {
        int t = (tid >= off) ? s[tid - off] : 0;
        __syncthreads();
        s[tid] += t;
        __syncthreads();
    }
    bstart[tid] = s[tid] - v;
    if (tid == NB - 1) bstart[NB] = s[NB - 1];
}

__global__ __launch_bounds__(256) void bin_kernel(const void* __restrict__ ei,
                                                  const int* __restrict__ flag,
                                                  const int* __restrict__ hist,
                                                  const int* __restrict__ bstart,
                                                  int2* __restrict__ binned, int e, int shift) {
    __shared__ int c[NB];
    c[threadIdx.x] = 0;
    __syncthreads();
    int is64 = (*flag == 0);
    int base = blockIdx.x * BCHUNK;
    #pragma unroll
    for (int k = 0; k < BCHUNK / 256; ++k) {
        int i = base + k * 256 + threadIdx.x;
        if (i < e) {
            int sN = edge_at(ei, i, is64);
            int d  = edge_at(ei, e + i, is64);
            int b  = d >> shift;
            int r  = atomicAdd(&c[b], 1);
            int pos = bstart[b] + hist[blockIdx.x * NB + b] + r;
            binned[pos] = make_int2(sN, d);
        }
    }
}

// ---------------- CSR finalize: per-bucket count + scan + rs/dis + scatter, all in LDS ----------------
__global__ __launch_bounds__(256) void finalize_bucket_kernel(
    const int2* __restrict__ binned, const int* __restrict__ bstart,
    int* __restrict__ rs, float* __restrict__ dis, int* __restrict__ csr,
    int shift, int n, int e) {
    __shared__ int lc[MAXW];
    __shared__ int ps[256];
    int b = blockIdx.x;
    int tid = threadIdx.x;
    int dbase = b << shift;
    int W = 1 << shift;
    for (int i = tid; i < W; i += 256) lc[i] = 0;
    __syncthreads();
    int beg = bstart[b], end = bstart[b + 1];
    for (int i = beg + tid; i < end; i += 256)
        atomicAdd(&lc[binned[i].y - dbase], 1);
    __syncthreads();
    int chunk = (W + 255) >> 8;
    int s0 = tid * chunk;
    int sum = 0;
    for (int j = 0; j < chunk; ++j) {
        int idx = s0 + j;
        if (idx < W) sum += lc[idx];
    }
    ps[tid] = sum;
    __syncthreads();
    for (int off = 1; off < 256; off <<= 1) {
        int t = (tid >= off) ? ps[tid - off] : 0;
        __syncthreads();
        ps[tid] += t;
        __syncthreads();
    }
    int pref = (tid == 0) ? 0 : ps[tid - 1];
    for (int j = 0; j < chunk; ++j) {
        int idx = s0 + j;
        if (idx < W) {
            int c = lc[idx];
            if (dbase + idx < n) {
                rs[dbase + idx] = beg + pref;
                dis[dbase + idx] = rsqrtf((float)c + 1.0f);
            }
            lc[idx] = pref;
            pref += c;
        }
    }
    if (b == 0 && tid == 0) rs[n] = e;
    __syncthreads();
    for (int i = beg + tid; i < end; i += 256) {
        int2 p = binned[i];
        int pos = beg + atomicAdd(&lc[p.y - dbase], 1);
        csr[pos] = p.x;
    }
}

// ---------------- W split+transpose (both layers in one launch) ----------------
__global__ void wsplit_kernel(const float* __restrict__ W1, const float* __restrict__ W2,
                              unsigned short* __restrict__ WhT1, unsigned short* __restrict__ WlT1,
                              unsigned short* __restrict__ WhT2, unsigned short* __restrict__ WlT2) {
    int g = blockIdx.x * 256 + threadIdx.x;      // 0..32767
    const float* W = (g < 16384) ? W1 : W2;
    unsigned short* WhT = (g < 16384) ? WhT1 : WhT2;
    unsigned short* WlT = (g < 16384) ? WlT1 : WlT2;
    int idx = g & 16383;
    int k = idx >> 7, c = idx & 127;
    float w = W[idx];
    unsigned int u = __float_as_uint(w);
    unsigned short hi = (unsigned short)(u >> 16);
    float rem = w - __uint_as_float((unsigned int)hi << 16);
    unsigned short lo = (unsigned short)(__float_as_uint(rem) >> 16);
    WhT[c * 128 + k] = hi;
    WlT[c * 128 + k] = lo;
}

// ---------------- split-bf16 MFMA GEMM, fp16 output ----------------
__device__ __forceinline__ void split8(float4 a0, float4 a1, s16x8& h, s16x8& l) {
    float v[8] = {a0.x, a0.y, a0.z, a0.w, a1.x, a1.y, a1.z, a1.w};
    #pragma unroll
    for (int j = 0; j < 8; ++j) {
        unsigned int u = __float_as_uint(v[j]);
        unsigned short hi = (unsigned short)(u >> 16);
        float rem = v[j] - __uint_as_float((unsigned int)hi << 16);
        h[j] = (short)hi;
        l[j] = (short)(__float_as_uint(rem) >> 16);
    }
}

__global__ __launch_bounds__(256) void gemm_mfma_kernel(
    const float* __restrict__ X, const unsigned short* __restrict__ WhT,
    const unsigned short* __restrict__ WlT, const float* __restrict__ dis,
    f16* __restrict__ out, int n) {
    __shared__ unsigned short bsh[128 * 128];   // [col][k] bf16 hi, swizzled
    __shared__ unsigned short bsl[128 * 128];   // [col][k] bf16 lo, swizzled
    const int tid = threadIdx.x;

    #pragma unroll
    for (int it = 0; it < 8; ++it) {
        int idx = it * 256 + tid;
        int col = idx >> 4;
        int ch  = idx & 15;
        int byte = (col * 256 + ch * 16) ^ ((col & 7) << 4);
        *(uint4*)((char*)bsh + byte) = ((const uint4*)WhT)[idx];
        *(uint4*)((char*)bsl + byte) = ((const uint4*)WlT)[idx];
    }
    __syncthreads();

    const int lane = tid & 63;
    const int wv = tid >> 6;
    const int rbase = blockIdx.x * 128 + wv * 32;
    const int lr = lane & 15;
    const int lg = lane >> 4;

    f32x4 acc[2][8];
    #pragma unroll
    for (int rt = 0; rt < 2; ++rt)
        #pragma unroll
        for (int ct = 0; ct < 8; ++ct) acc[rt][ct] = (f32x4)0.f;

    #pragma unroll
    for (int kk = 0; kk < 4; ++kk) {
        const int k0 = kk * 32 + lg * 8;
        s16x8 bh[8], bl[8];
        #pragma unroll
        for (int ct = 0; ct < 8; ++ct) {
            int col = ct * 16 + lr;
            int byte = (col * 256 + k0 * 2) ^ ((col & 7) << 4);
            bh[ct] = *(const s16x8*)((const char*)bsh + byte);
            bl[ct] = *(const s16x8*)((const char*)bsl + byte);
        }
        #pragma unroll
        for (int rt = 0; rt < 2; ++rt) {
            int row = rbase + rt * 16 + lr;
            float4 a0 = make_float4(0.f, 0.f, 0.f, 0.f);
            float4 a1 = make_float4(0.f, 0.f, 0.f, 0.f);
            if (row < n) {
                a0 = *(const float4*)&X[(size_t)row * CH + k0];
                a1 = *(const float4*)&X[(size_t)row * CH + k0 + 4];
            }
            s16x8 ah, al;
            split8(a0, a1, ah, al);
            #pragma unroll
            for (int ct = 0; ct < 8; ++ct) {
                acc[rt][ct] = __builtin_amdgcn_mfma_f32_16x16x32_bf16(ah, bh[ct], acc[rt][ct], 0, 0, 0);
                acc[rt][ct] = __builtin_amdgcn_mfma_f32_16x16x32_bf16(al, bh[ct], acc[rt][ct], 0, 0, 0);
                acc[rt][ct] = __builtin_amdgcn_mfma_f32_16x16x32_bf16(ah, bl[ct], acc[rt][ct], 0, 0, 0);
            }
        }
    }

    #pragma unroll
    for (int rt = 0; rt < 2; ++rt) {
        #pragma unroll
        for (int reg = 0; reg < 4; ++reg) {
            int row = rbase + rt * 16 + lg * 4 + reg;
            if (row < n) {
                float d = dis[row];
                #pragma unroll
                for (int ct = 0; ct < 8; ++ct) {
                    int col = ct * 16 + lr;
                    out[(size_t)row * CH + col] = (f16)(acc[rt][ct][reg] * d);
                }
            }
        }
    }
}

// ---------------- aggregation (128 ch): wave per dst, f16x2/lane gather, fp32 accum ----------------
// Mode A (W3c == null): out[dst][:] = relu(dis*sum + bias)  (fp32)
// Mode B (W3c != null): fused layer-3 transform -> H3[dst][0:2]
__global__ __launch_bounds__(256) void agg128_kernel(
    const f16* __restrict__ Hs, const int* __restrict__ rs, const int* __restrict__ csr,
    const float* __restrict__ dis, const float* __restrict__ bias,
    float* __restrict__ out, int n,
    const float* __restrict__ W3c, float* __restrict__ H3) {
    int dst = blockIdx.x * 4 + (threadIdx.x >> 6);
    if (dst >= n) return;
    int lane = threadIdx.x & 63;
    int c = lane * 2;
    f16x2 sv = *(const f16x2*)&Hs[(size_t)dst * CH + c];
    float2 acc = make_float2((float)sv.x, (float)sv.y);
    int beg = rs[dst], end = rs[dst + 1];
    int last = end - 1;
    for (int i = beg; i < end; i += 4) {
        int i1 = i + 1 <= last ? i + 1 : last;
        int i2 = i + 2 <= last ? i + 2 : last;
        int i3 = i + 3 <= last ? i + 3 : last;
        int s0 = csr[i], s1 = csr[i1], s2 = csr[i2], s3 = csr[i3];
        f16x2 v0 = *(const f16x2*)&Hs[(size_t)s0 * CH + c];
        f16x2 v1 = *(const f16x2*)&Hs[(size_t)s1 * CH + c];
        f16x2 v2 = *(const f16x2*)&Hs[(size_t)s2 * CH + c];
        f16x2 v3 = *(const f16x2*)&Hs[(size_t)s3 * CH + c];
        float m1 = (i + 1 < end) ? 1.f : 0.f;
        float m2 = (i + 2 < end) ? 1.f : 0.f;
        float m3 = (i + 3 < end) ? 1.f : 0.f;
        acc.x += (float)v0.x + m1 * (float)v1.x + (m2 * (float)v2.x + m3 * (float)v3.x);
        acc.y += (float)v0.y + m1 * (float)v1.y + (m2 * (float)v2.y + m3 * (float)v3.y);
    }
    float d = dis[dst];
    float2 b = *(const float2*)&bias[c];
    float o0 = fmaxf(fmaf(acc.x, d, b.x), 0.f);
    float o1 = fmaxf(fmaf(acc.y, d, b.y), 0.f);
    if (W3c == nullptr) {
        *(float2*)&out[(size_t)dst * CH + c] = make_float2(o0, o1);
    } else {
        float4 w4 = *(const float4*)&W3c[lane * 4];
        float a0 = o0 * w4.x + o1 * w4.z;
        float a1 = o0 * w4.y + o1 * w4.w;
        #pragma unroll
        for (int off = 32; off > 0; off >>= 1) {
            a0 += __shfl_xor(a0, off, 64);
            a1 += __shfl_xor(a1, off, 64);
        }
        if (lane == 0) {
            H3[dst * 2]     = a0 * d;
            H3[dst * 2 + 1] = a1 * d;
        }
    }
}

// ---------------- layer 3 aggregation (2 ch): thread per dst, 4-deep ----------------
__global__ void agg_out_kernel(const float* __restrict__ H3, const int* __restrict__ rs,
                               const int* __restrict__ csr, const float* __restrict__ dis,
                               const float* __restrict__ b3, float* __restrict__ out, int n) {
    int dst = blockIdx.x * blockDim.x + threadIdx.x;
    if (dst >= n) return;
    float2 acc = *(const float2*)&H3[dst * 2];
    int beg = rs[dst], end = rs[dst + 1];
    int last = end - 1;
    for (int i = beg; i < end; i += 4) {
        int i1 = i + 1 <= last ? i + 1 : last;
        int i2 = i + 2 <= last ? i + 2 : last;
        int i3 = i + 3 <= last ? i + 3 : last;
        int s0 = csr[i], s1 = csr[i1], s2 = csr[i2], s3 = csr[i3];
        float2 v0 = *(const float2*)&H3[s0 * 2];
        float2 v1 = *(const float2*)&H3[s1 * 2];
        float2 v2 = *(const float2*)&H3[s2 * 2];
        float2 v3 = *(const float2*)&H3[s3 * 2];
        float m1 = (i + 1 < end) ? 1.f : 0.f;
        float m2 = (i + 2 < end) ? 1.f : 0.f;
        float m3 = (i + 3 < end) ? 1.f : 0.f;
        acc.x += v0.x + m1 * v1.x + (m2 * v2.x + m3 * v3.x);
        acc.y += v0.y + m1 * v1.y + (m2 * v2.y + m3 * v3.y);
    }
    float d = dis[dst];
    out[dst * 2]     = fmaf(acc.x, d, b3[0]);
    out[dst * 2 + 1] = fmaf(acc.y, d, b3[1]);
}

extern "C" void kernel_launch(void* const* d_in, const int* in_sizes, int n_in,
                              void* d_out, int out_size, void* d_ws, size_t ws_size,
                              hipStream_t stream) {
    const float* x  = (const float*)d_in[0];
    const void*  ei = d_in[1];
    const float* W1 = (const float*)d_in[2];
    const float* b1 = (const float*)d_in[3];
    const float* W2 = (const float*)d_in[4];
    const float* b2 = (const float*)d_in[5];
    const float* W3 = (const float*)d_in[6];
    const float* b3 = (const float*)d_in[7];
    float* out = (float*)d_out;

    const int n = in_sizes[0] / CH;      // 100000
    const int e = in_sizes[1] / 2;       // 1600000

    char* w = (char*)d_ws;
    size_t off = 0;
    auto alloc = [&](size_t bytes) { char* p = w + off; off = (off + bytes + 255) & ~(size_t)255; return p; };
    float* bufA   = (float*)alloc((size_t)n * CH * 4);   // f16 H' table; aliases `binned` during CSR build
    float* bufB   = (float*)alloc((size_t)n * CH * 4);   // fp32 h1; aliases `hist` during CSR build
    int*   csr    = (int*)  alloc((size_t)e * 4);
    float* dis    = (float*)alloc((size_t)n * 4);
    int*   rs     = (int*)  alloc(((size_t)n + 1) * 4);
    float* H3     = (float*)alloc((size_t)n * 2 * 4);
    int*   btot   = (int*)  alloc(NB * 4);
    int*   bstart = (int*)  alloc((NB + 1) * 4);
    unsigned short* WhT1 = (unsigned short*)alloc(128 * 128 * 2);
    unsigned short* WlT1 = (unsigned short*)alloc(128 * 128 * 2);
    unsigned short* WhT2 = (unsigned short*)alloc(128 * 128 * 2);
    unsigned short* WlT2 = (unsigned short*)alloc(128 * 128 * 2);
    char* zbase   = w + off;
    int*   flag   = (int*)  alloc(256);
    size_t zbytes = (size_t)((w + off) - zbase);

    int2* binned = (int2*)bufA;          // e*8 = 12.8MB <= 51.2MB
    int*  hist   = (int*)bufB;           // nblk*NB*4 ~ 400KB
    f16*  Htab   = (f16*)bufA;           // n*CH*2 = 25.6MB (after binning done)

    int shift = 0;
    while (((n - 1) >> shift) >= NB) ++shift;

    hipMemsetAsync(zbase, 0, zbytes, stream);

    int nwords = 2 * e < 16384 ? 2 * e : 16384;
    detect_kernel<<<8, 1024, 0, stream>>>((const int*)ei, flag, nwords);

    wsplit_kernel<<<128, 256, 0, stream>>>(W1, W2, WhT1, WlT1, WhT2, WlT2);

    // ---- CSR build ----
    const int nblk = (e + BCHUNK - 1) / BCHUNK;
    hist_kernel<<<nblk, NB, 0, stream>>>(ei, flag, hist, e, shift);
    scan_col_kernel<<<NB, 512, 0, stream>>>(hist, btot, nblk);
    scan_btot_kernel<<<1, NB, 0, stream>>>(btot, bstart);
    bin_kernel<<<nblk, NB, 0, stream>>>(ei, flag, hist, bstart, binned, e, shift);
    finalize_bucket_kernel<<<NB, 256, 0, stream>>>(binned, bstart, rs, dis, csr, shift, n, e);

    const int mfmaGrid = (n + 127) / 128;
    const int aggGrid  = (n + 3) / 4;

    // layer 1  (gemm writes fp16 table into bufA — binned no longer needed)
    gemm_mfma_kernel<<<mfmaGrid, 256, 0, stream>>>(x, WhT1, WlT1, dis, Htab, n);
    agg128_kernel<<<aggGrid, 256, 0, stream>>>(Htab, rs, csr, dis, b1, bufB, n, nullptr, nullptr);
    // layer 2 (+ fused layer-3 transform in agg epilogue)
    gemm_mfma_kernel<<<mfmaGrid, 256, 0, stream>>>(bufB, WhT2, WlT2, dis, Htab, n);
    agg128_kernel<<<aggGrid, 256, 0, stream>>>(Htab, rs, csr, dis, b2, nullptr, n, W3, H3);
    // layer 3 aggregation
    agg_out_kernel<<<(n + 255) / 256, 256, 0, stream>>>(H3, rs, csr, dis, b3, out, n);
}

// Round 10
// 250.186 us; speedup vs baseline: 1.7594x; 1.0617x over previous
//
#include <hip/hip_runtime.h>

#define CH 128
#define BCHUNK 4096   // edges per binning block (16 per thread @ 256 thr)
#define NB 256        // max buckets
#define MAXW 2048     // max bucket width for LDS count/cursor (shift <= 11)

typedef float f32x4 __attribute__((ext_vector_type(4)));
typedef short s16x8 __attribute__((ext_vector_type(8)));
typedef _Float16 f16;
typedef _Float16 f16x2 __attribute__((ext_vector_type(2)));

// ---------------- edge dtype detection (int32 vs int64), sampled ----------------
__global__ void detect_kernel(const int* __restrict__ ei, int* __restrict__ flag, int nwords) {
    int w = 2 * threadIdx.x + 1 + 2048 * blockIdx.x;
    if (w < nwords) {
        if (ei[w] != 0) atomicOr(flag, 1);
    }
}

__device__ __forceinline__ int edge_at(const void* ei, int idx, int is64) {
    if (is64) return (int)((const long long*)ei)[idx];
    return ((const int*)ei)[idx];
}

// ---------------- CSR build pass A: histogram / scans / bin ----------------
__global__ __launch_bounds__(256) void hist_kernel(const void* __restrict__ ei,
                                                   const int* __restrict__ flag,
                                                   int* __restrict__ hist, int e, int shift) {
    __shared__ int h[NB];
    h[threadIdx.x] = 0;
    __syncthreads();
    int is64 = (*flag == 0);
    int base = blockIdx.x * BCHUNK;
    #pragma unroll
    for (int k = 0; k < BCHUNK / 256; ++k) {
        int i = base + k * 256 + threadIdx.x;
        if (i < e) {
            int d = edge_at(ei, e + i, is64);
            atomicAdd(&h[d >> shift], 1);
        }
    }
    __syncthreads();
    hist[blockIdx.x * NB + threadIdx.x] = h[threadIdx.x];
}

__global__ __launch_bounds__(512) void scan_col_kernel(int* __restrict__ hist,
                                                       int* __restrict__ btot, int nblk) {
    __shared__ int s[512];
    int b = blockIdx.x;
    int tid = threadIdx.x;
    int v = (tid < nblk) ? hist[tid * NB + b] : 0;
    s[tid] = v;
    __syncthreads();
    for (int off = 1; off < 512; off <<= 1) {
        int t = (tid >= off) ? s[tid - off] : 0;
        __syncthreads();
        s[tid] += t;
        __syncthreads();
    }
    if (tid < nblk) hist[tid * NB + b] = s[tid] - v;   // exclusive
    if (tid == 511) btot[b] = s[511];
}

// exclusive scan of NB values; also writes total at out[NB]
__global__ __launch_bounds__(NB) void scan_nb_kernel(const int* __restrict__ in,
                                                     int* __restrict__ outp) {
    __shared__ int s[NB];
    int tid = threadIdx.x;
    int v = in[tid];
    s[tid] = v;
    __syncthreads();
    for (int off = 1; off < NB; off <<= 1) {
        int t = (tid >= off) ? s[tid - off] : 0;
        __syncthreads();
        s[tid] += t;
        __syncthreads();
    }
    outp[tid] = s[tid] - v;
    if (tid == NB - 1) outp[NB] = s[NB - 1];
}

__global__ __launch_bounds__(256) void bin_kernel(const void* __restrict__ ei,
                                                  const int* __restrict__ flag,
                                                  const int* __restrict__ hist,
                                                  const int* __restrict__ bstart,
                                                  int2* __restrict__ binned, int e, int shift) {
    __shared__ int c[NB];
    c[threadIdx.x] = 0;
    __syncthreads();
    int is64 = (*flag == 0);
    int base = blockIdx.x * BCHUNK;
    #pragma unroll
    for (int k = 0; k < BCHUNK / 256; ++k) {
        int i = base + k * 256 + threadIdx.x;
        if (i < e) {
            int sN = edge_at(ei, i, is64);
            int d  = edge_at(ei, e + i, is64);
            int b  = d >> shift;
            int r  = atomicAdd(&c[b], 1);
            int pos = bstart[b] + hist[blockIdx.x * NB + b] + r;
            binned[pos] = make_int2(sN, d);
        }
    }
}

// ---------------- finalize A: per-bucket degree count -> cntg, padded bucket totals ----------------
__global__ __launch_bounds__(256) void finalize_a_kernel(
    const int2* __restrict__ binned, const int* __restrict__ bstart,
    int* __restrict__ cntg, int* __restrict__ ptot, int shift, int n) {
    __shared__ int lc[MAXW];
    __shared__ int ps[256];
    int b = blockIdx.x, tid = threadIdx.x;
    int dbase = b << shift, W = 1 << shift;
    for (int i = tid; i < W; i += 256) lc[i] = 0;
    __syncthreads();
    int beg = bstart[b], end = bstart[b + 1];
    for (int i = beg + tid; i < end; i += 256)
        atomicAdd(&lc[binned[i].y - dbase], 1);
    __syncthreads();
    int chunk = (W + 255) >> 8;
    int s0 = tid * chunk;
    int sum = 0;
    #pragma unroll 8
    for (int j = 0; j < 8; ++j) {
        if (j < chunk) {
            int idx = s0 + j;
            if (idx < W) {
                int c = lc[idx];
                if (dbase + idx < n) cntg[dbase + idx] = c;
                sum += (c + 3) & ~3;
            }
        }
    }
    ps[tid] = sum;
    __syncthreads();
    #pragma unroll
    for (int off = 128; off > 0; off >>= 1) {
        if (tid < off) ps[tid] += ps[tid + off];
        __syncthreads();
    }
    if (tid == 0) ptot[b] = ps[0];
}

// ---------------- finalize B: padded rs/dis, pad-fill, scatter; zero pad rows ----------------
__global__ __launch_bounds__(256) void finalize_b_kernel(
    const int2* __restrict__ binned, const int* __restrict__ bstart,
    const int* __restrict__ cntg, const int* __restrict__ pstart,
    int* __restrict__ rs, float* __restrict__ dis, int* __restrict__ csr,
    f16* __restrict__ HtabPadRow, float* __restrict__ H3, int shift, int n) {
    __shared__ int lc[MAXW];   // padded local prefix -> scatter cursor
    __shared__ int ps[256];
    int b = blockIdx.x, tid = threadIdx.x;
    int dbase = b << shift, W = 1 << shift;
    int pb = pstart[b];
    int chunk = (W + 255) >> 8;
    int s0 = tid * chunk;
    int cc[8];
    int sum = 0;
    #pragma unroll 8
    for (int j = 0; j < 8; ++j) {
        cc[j] = 0;
        if (j < chunk) {
            int idx = s0 + j;
            int c = (idx < W && dbase + idx < n) ? cntg[dbase + idx] : 0;
            cc[j] = c;
            sum += (c + 3) & ~3;
        }
    }
    ps[tid] = sum;
    __syncthreads();
    for (int off = 1; off < 256; off <<= 1) {
        int t = (tid >= off) ? ps[tid - off] : 0;
        __syncthreads();
        ps[tid] += t;
        __syncthreads();
    }
    int pref = (tid == 0) ? 0 : ps[tid - 1];
    #pragma unroll 8
    for (int j = 0; j < 8; ++j) {
        if (j < chunk) {
            int idx = s0 + j;
            if (idx < W) {
                int c = cc[j];
                int pc = (c + 3) & ~3;
                if (dbase + idx < n) {
                    rs[dbase + idx] = pb + pref;
                    dis[dbase + idx] = rsqrtf((float)c + 1.0f);
                    for (int k = c; k < pc; ++k) csr[pb + pref + k] = n;  // sentinel -> zero row
                }
                lc[idx] = pref;
                pref += pc;
            }
        }
    }
    __syncthreads();
    int beg = bstart[b], end = bstart[b + 1];
    for (int i = beg + tid; i < end; i += 256) {
        int2 p = binned[i];
        int pos = pb + atomicAdd(&lc[p.y - dbase], 1);
        csr[pos] = p.x;
    }
    if (b == 0) {
        if (tid < 64) ((unsigned*)HtabPadRow)[tid] = 0;            // zero f16 row n (256B)
        if (tid == 64) { H3[2 * (size_t)n] = 0.f; H3[2 * (size_t)n + 1] = 0.f; }
        if (tid == 65) rs[n] = pstart[NB];
    }
}

// ---------------- W split+transpose (both layers in one launch) ----------------
__global__ void wsplit_kernel(const float* __restrict__ W1, const float* __restrict__ W2,
                              unsigned short* __restrict__ WhT1, unsigned short* __restrict__ WlT1,
                              unsigned short* __restrict__ WhT2, unsigned short* __restrict__ WlT2) {
    int g = blockIdx.x * 256 + threadIdx.x;      // 0..32767
    const float* W = (g < 16384) ? W1 : W2;
    unsigned short* WhT = (g < 16384) ? WhT1 : WhT2;
    unsigned short* WlT = (g < 16384) ? WlT1 : WlT2;
    int idx = g & 16383;
    int k = idx >> 7, c = idx & 127;
    float w = W[idx];
    unsigned int u = __float_as_uint(w);
    unsigned short hi = (unsigned short)(u >> 16);
    float rem = w - __uint_as_float((unsigned int)hi << 16);
    unsigned short lo = (unsigned short)(__float_as_uint(rem) >> 16);
    WhT[c * 128 + k] = hi;
    WlT[c * 128 + k] = lo;
}

// ---------------- split-bf16 MFMA GEMM, fp16 output ----------------
__device__ __forceinline__ void split8(float4 a0, float4 a1, s16x8& h, s16x8& l) {
    float v[8] = {a0.x, a0.y, a0.z, a0.w, a1.x, a1.y, a1.z, a1.w};
    #pragma unroll
    for (int j = 0; j < 8; ++j) {
        unsigned int u = __float_as_uint(v[j]);
        unsigned short hi = (unsigned short)(u >> 16);
        float rem = v[j] - __uint_as_float((unsigned int)hi << 16);
        h[j] = (short)hi;
        l[j] = (short)(__float_as_uint(rem) >> 16);
    }
}

__global__ __launch_bounds__(256) void gemm_mfma_kernel(
    const float* __restrict__ X, const unsigned short* __restrict__ WhT,
    const unsigned short* __restrict__ WlT, const float* __restrict__ dis,
    f16* __restrict__ out, int n) {
    __shared__ unsigned short bsh[128 * 128];   // [col][k] bf16 hi, swizzled
    __shared__ unsigned short bsl[128 * 128];   // [col][k] bf16 lo, swizzled
    const int tid = threadIdx.x;

    #pragma unroll
    for (int it = 0; it < 8; ++it) {
        int idx = it * 256 + tid;
        int col = idx >> 4;
        int ch  = idx & 15;
        int byte = (col * 256 + ch * 16) ^ ((col & 7) << 4);
        *(uint4*)((char*)bsh + byte) = ((const uint4*)WhT)[idx];
        *(uint4*)((char*)bsl + byte) = ((const uint4*)WlT)[idx];
    }
    __syncthreads();

    const int lane = tid & 63;
    const int wv = tid >> 6;
    const int rbase = blockIdx.x * 128 + wv * 32;
    const int lr = lane & 15;
    const int lg = lane >> 4;

    f32x4 acc[2][8];
    #pragma unroll
    for (int rt = 0; rt < 2; ++rt)
        #pragma unroll
        for (int ct = 0; ct < 8; ++ct) acc[rt][ct] = (f32x4)0.f;

    #pragma unroll
    for (int kk = 0; kk < 4; ++kk) {
        const int k0 = kk * 32 + lg * 8;
        s16x8 bh[8], bl[8];
        #pragma unroll
        for (int ct = 0; ct < 8; ++ct) {
            int col = ct * 16 + lr;
            int byte = (col * 256 + k0 * 2) ^ ((col & 7) << 4);
            bh[ct] = *(const s16x8*)((const char*)bsh + byte);
            bl[ct] = *(const s16x8*)((const char*)bsl + byte);
        }
        #pragma unroll
        for (int rt = 0; rt < 2; ++rt) {
            int row = rbase + rt * 16 + lr;
            float4 a0 = make_float4(0.f, 0.f, 0.f, 0.f);
            float4 a1 = make_float4(0.f, 0.f, 0.f, 0.f);
            if (row < n) {
                a0 = *(const float4*)&X[(size_t)row * CH + k0];
                a1 = *(const float4*)&X[(size_t)row * CH + k0 + 4];
            }
            s16x8 ah, al;
            split8(a0, a1, ah, al);
            #pragma unroll
            for (int ct = 0; ct < 8; ++ct) {
                acc[rt][ct] = __builtin_amdgcn_mfma_f32_16x16x32_bf16(ah, bh[ct], acc[rt][ct], 0, 0, 0);
                acc[rt][ct] = __builtin_amdgcn_mfma_f32_16x16x32_bf16(al, bh[ct], acc[rt][ct], 0, 0, 0);
                acc[rt][ct] = __builtin_amdgcn_mfma_f32_16x16x32_bf16(ah, bl[ct], acc[rt][ct], 0, 0, 0);
            }
        }
    }

    #pragma unroll
    for (int rt = 0; rt < 2; ++rt) {
        #pragma unroll
        for (int reg = 0; reg < 4; ++reg) {
            int row = rbase + rt * 16 + lg * 4 + reg;
            if (row < n) {
                float d = dis[row];
                #pragma unroll
                for (int ct = 0; ct < 8; ++ct) {
                    int col = ct * 16 + lr;
                    out[(size_t)row * CH + col] = (f16)(acc[rt][ct][reg] * d);
                }
            }
        }
    }
}

// ---------------- aggregation (128 ch): wave per dst, scalarized indices, padded CSR ----------------
// Mode A (W3c == null): out[dst][:] = relu(dis*sum + bias)  (fp32)
// Mode B (W3c != null): fused layer-3 transform -> H3[dst][0:2]
__global__ __launch_bounds__(256) void agg128_kernel(
    const f16* __restrict__ Hs, const int* __restrict__ rs, const int* __restrict__ csr,
    const float* __restrict__ dis, const float* __restrict__ bias,
    float* __restrict__ out, int n,
    const float* __restrict__ W3c, float* __restrict__ H3) {
    int dst = blockIdx.x * 4 + (threadIdx.x >> 6);
    dst = __builtin_amdgcn_readfirstlane(dst);      // wave-uniform -> SGPR
    if (dst >= n) return;
    int lane = threadIdx.x & 63;
    int c = lane * 2;
    f16x2 sv = *(const f16x2*)&Hs[(size_t)dst * CH + c];
    float2 acc = make_float2((float)sv.x, (float)sv.y);
    int beg = rs[dst], end = rs[dst + 1];           // padded region, length % 4 == 0
    for (int i = beg; i < end; i += 4) {
        int s0 = csr[i], s1 = csr[i + 1], s2 = csr[i + 2], s3 = csr[i + 3];
        f16x2 v0 = *(const f16x2*)&Hs[(size_t)s0 * CH + c];
        f16x2 v1 = *(const f16x2*)&Hs[(size_t)s1 * CH + c];
        f16x2 v2 = *(const f16x2*)&Hs[(size_t)s2 * CH + c];
        f16x2 v3 = *(const f16x2*)&Hs[(size_t)s3 * CH + c];
        acc.x += ((float)v0.x + (float)v1.x) + ((float)v2.x + (float)v3.x);
        acc.y += ((float)v0.y + (float)v1.y) + ((float)v2.y + (float)v3.y);
    }
    float d = dis[dst];
    float2 b = *(const float2*)&bias[c];
    float o0 = fmaxf(fmaf(acc.x, d, b.x), 0.f);
    float o1 = fmaxf(fmaf(acc.y, d, b.y), 0.f);
    if (W3c == nullptr) {
        *(float2*)&out[(size_t)dst * CH + c] = make_float2(o0, o1);
    } else {
        float4 w4 = *(const float4*)&W3c[lane * 4];
        float a0 = o0 * w4.x + o1 * w4.z;
        float a1 = o0 * w4.y + o1 * w4.w;
        #pragma unroll
        for (int off = 32; off > 0; off >>= 1) {
            a0 += __shfl_xor(a0, off, 64);
            a1 += __shfl_xor(a1, off, 64);
        }
        if (lane == 0) {
            H3[dst * 2]     = a0 * d;
            H3[dst * 2 + 1] = a1 * d;
        }
    }
}

// ---------------- layer 3 aggregation (2 ch): thread per dst, padded CSR ----------------
__global__ void agg_out_kernel(const float* __restrict__ H3, const int* __restrict__ rs,
                               const int* __restrict__ csr, const float* __restrict__ dis,
                               const float* __restrict__ b3, float* __restrict__ out, int n) {
    int dst = blockIdx.x * blockDim.x + threadIdx.x;
    if (dst >= n) return;
    float2 acc = *(const float2*)&H3[dst * 2];
    int beg = rs[dst], end = rs[dst + 1];
    for (int i = beg; i < end; i += 4) {
        int s0 = csr[i], s1 = csr[i + 1], s2 = csr[i + 2], s3 = csr[i + 3];
        float2 v0 = *(const float2*)&H3[s0 * 2];
        float2 v1 = *(const float2*)&H3[s1 * 2];
        float2 v2 = *(const float2*)&H3[s2 * 2];
        float2 v3 = *(const float2*)&H3[s3 * 2];
        acc.x += (v0.x + v1.x) + (v2.x + v3.x);
        acc.y += (v0.y + v1.y) + (v2.y + v3.y);
    }
    float d = dis[dst];
    out[dst * 2]     = fmaf(acc.x, d, b3[0]);
    out[dst * 2 + 1] = fmaf(acc.y, d, b3[1]);
}

extern "C" void kernel_launch(void* const* d_in, const int* in_sizes, int n_in,
                              void* d_out, int out_size, void* d_ws, size_t ws_size,
                              hipStream_t stream) {
    const float* x  = (const float*)d_in[0];
    const void*  ei = d_in[1];
    const float* W1 = (const float*)d_in[2];
    const float* b1 = (const float*)d_in[3];
    const float* W2 = (const float*)d_in[4];
    const float* b2 = (const float*)d_in[5];
    const float* W3 = (const float*)d_in[6];
    const float* b3 = (const float*)d_in[7];
    float* out = (float*)d_out;

    const int n = in_sizes[0] / CH;      // 100000
    const int e = in_sizes[1] / 2;       // 1600000

    char* w = (char*)d_ws;
    size_t off = 0;
    auto alloc = [&](size_t bytes) { char* p = w + off; off = (off + bytes + 255) & ~(size_t)255; return p; };
    float* bufA   = (float*)alloc((size_t)n * CH * 4);      // f16 Htab (n+1 rows); aliases `binned`
    float* bufB   = (float*)alloc((size_t)n * CH * 4);      // fp32 h1; aliases hist/cntg
    int*   csr    = (int*)  alloc(((size_t)e + 3 * (size_t)n + 64) * 4);   // padded
    float* dis    = (float*)alloc((size_t)n * 4);
    int*   rs     = (int*)  alloc(((size_t)n + 1) * 4);
    float* H3     = (float*)alloc(((size_t)n + 1) * 2 * 4); // +1 zero pad row
    int*   btot   = (int*)  alloc(NB * 4);
    int*   bstart = (int*)  alloc((NB + 1) * 4);
    int*   ptot   = (int*)  alloc(NB * 4);
    int*   pstart = (int*)  alloc((NB + 1) * 4);
    unsigned short* WhT1 = (unsigned short*)alloc(128 * 128 * 2);
    unsigned short* WlT1 = (unsigned short*)alloc(128 * 128 * 2);
    unsigned short* WhT2 = (unsigned short*)alloc(128 * 128 * 2);
    unsigned short* WlT2 = (unsigned short*)alloc(128 * 128 * 2);
    char* zbase   = w + off;
    int*   flag   = (int*)  alloc(256);
    size_t zbytes = (size_t)((w + off) - zbase);

    int2* binned = (int2*)bufA;          // e*8 = 12.8MB
    int*  hist   = (int*)bufB;           // nblk*NB*4 ~ 400KB
    int*  cntg   = (int*)bufB + 512 * NB;  // after hist region (512KB offset)
    f16*  Htab   = (f16*)bufA;           // (n+1)*CH*2 = 25.6MB (after binning done)

    int shift = 0;
    while (((n - 1) >> shift) >= NB) ++shift;

    hipMemsetAsync(zbase, 0, zbytes, stream);

    int nwords = 2 * e < 16384 ? 2 * e : 16384;
    detect_kernel<<<8, 1024, 0, stream>>>((const int*)ei, flag, nwords);

    wsplit_kernel<<<128, 256, 0, stream>>>(W1, W2, WhT1, WlT1, WhT2, WlT2);

    // ---- CSR build (bucket-major, padded to %4 with sentinel n) ----
    const int nblk = (e + BCHUNK - 1) / BCHUNK;
    hist_kernel<<<nblk, NB, 0, stream>>>(ei, flag, hist, e, shift);
    scan_col_kernel<<<NB, 512, 0, stream>>>(hist, btot, nblk);
    scan_nb_kernel<<<1, NB, 0, stream>>>(btot, bstart);
    bin_kernel<<<nblk, NB, 0, stream>>>(ei, flag, hist, bstart, binned, e, shift);
    finalize_a_kernel<<<NB, 256, 0, stream>>>(binned, bstart, cntg, ptot, shift, n);
    scan_nb_kernel<<<1, NB, 0, stream>>>(ptot, pstart);
    finalize_b_kernel<<<NB, 256, 0, stream>>>(binned, bstart, cntg, pstart, rs, dis, csr,
                                              Htab + (size_t)n * CH, H3, shift, n);

    const int mfmaGrid = (n + 127) / 128;
    const int aggGrid  = (n + 3) / 4;

    // layer 1  (gemm writes fp16 table into bufA — binned no longer needed)
    gemm_mfma_kernel<<<mfmaGrid, 256, 0, stream>>>(x, WhT1, WlT1, dis, Htab, n);
    agg128_kernel<<<aggGrid, 256, 0, stream>>>(Htab, rs, csr, dis, b1, bufB, n, nullptr, nullptr);
    // layer 2 (+ fused layer-3 transform in agg epilogue)
    gemm_mfma_kernel<<<mfmaGrid, 256, 0, stream>>>(bufB, WhT2, WlT2, dis, Htab, n);
    agg128_kernel<<<aggGrid, 256, 0, stream>>>(Htab, rs, csr, dis, b2, nullptr, n, W3, H3);
    // layer 3 aggregation
    agg_out_kernel<<<(n + 255) / 256, 256, 0, stream>>>(H3, rs, csr, dis, b3, out, n);
}

// Round 11
// 248.190 us; speedup vs baseline: 1.7736x; 1.0080x over previous
//
#include <hip/hip_runtime.h>

#define CH 128
#define BCHUNK 4096   // edges per binning block (16 per thread @ 256 thr)
#define NB 256        // max buckets
#define MAXW 2048     // max bucket width for LDS count/cursor (shift <= 11)

typedef float f32x4 __attribute__((ext_vector_type(4)));
typedef short s16x8 __attribute__((ext_vector_type(8)));
typedef _Float16 f16;
typedef _Float16 f16x2 __attribute__((ext_vector_type(2)));
typedef _Float16 f16x8 __attribute__((ext_vector_type(8)));

// ---------------- edge dtype detection (int32 vs int64), sampled ----------------
__global__ void detect_kernel(const int* __restrict__ ei, int* __restrict__ flag, int nwords) {
    int w = 2 * threadIdx.x + 1 + 2048 * blockIdx.x;
    if (w < nwords) {
        if (ei[w] != 0) atomicOr(flag, 1);
    }
}

__device__ __forceinline__ int edge_at(const void* ei, int idx, int is64) {
    if (is64) return (int)((const long long*)ei)[idx];
    return ((const int*)ei)[idx];
}

// ---------------- CSR build pass A: histogram / scans / bin ----------------
__global__ __launch_bounds__(256) void hist_kernel(const void* __restrict__ ei,
                                                   const int* __restrict__ flag,
                                                   int* __restrict__ hist, int e, int shift) {
    __shared__ int h[NB];
    h[threadIdx.x] = 0;
    __syncthreads();
    int is64 = (*flag == 0);
    int base = blockIdx.x * BCHUNK;
    #pragma unroll
    for (int k = 0; k < BCHUNK / 256; ++k) {
        int i = base + k * 256 + threadIdx.x;
        if (i < e) {
            int d = edge_at(ei, e + i, is64);
            atomicAdd(&h[d >> shift], 1);
        }
    }
    __syncthreads();
    hist[blockIdx.x * NB + threadIdx.x] = h[threadIdx.x];
}

__global__ __launch_bounds__(512) void scan_col_kernel(int* __restrict__ hist,
                                                       int* __restrict__ btot, int nblk) {
    __shared__ int s[512];
    int b = blockIdx.x;
    int tid = threadIdx.x;
    int v = (tid < nblk) ? hist[tid * NB + b] : 0;
    s[tid] = v;
    __syncthreads();
    for (int off = 1; off < 512; off <<= 1) {
        int t = (tid >= off) ? s[tid - off] : 0;
        __syncthreads();
        s[tid] += t;
        __syncthreads();
    }
    if (tid < nblk) hist[tid * NB + b] = s[tid] - v;   // exclusive
    if (tid == 511) btot[b] = s[511];
}

// exclusive scan of NB values; also writes total at out[NB]
__global__ __launch_bounds__(NB) void scan_nb_kernel(const int* __restrict__ in,
                                                     int* __restrict__ outp) {
    __shared__ int s[NB];
    int tid = threadIdx.x;
    int v = in[tid];
    s[tid] = v;
    __syncthreads();
    for (int off = 1; off < NB; off <<= 1) {
        int t = (tid >= off) ? s[tid - off] : 0;
        __syncthreads();
        s[tid] += t;
        __syncthreads();
    }
    outp[tid] = s[tid] - v;
    if (tid == NB - 1) outp[NB] = s[NB - 1];
}

__global__ __launch_bounds__(256) void bin_kernel(const void* __restrict__ ei,
                                                  const int* __restrict__ flag,
                                                  const int* __restrict__ hist,
                                                  const int* __restrict__ bstart,
                                                  int2* __restrict__ binned, int e, int shift) {
    __shared__ int c[NB];
    c[threadIdx.x] = 0;
    __syncthreads();
    int is64 = (*flag == 0);
    int base = blockIdx.x * BCHUNK;
    #pragma unroll
    for (int k = 0; k < BCHUNK / 256; ++k) {
        int i = base + k * 256 + threadIdx.x;
        if (i < e) {
            int sN = edge_at(ei, i, is64);
            int d  = edge_at(ei, e + i, is64);
            int b  = d >> shift;
            int r  = atomicAdd(&c[b], 1);
            int pos = bstart[b] + hist[blockIdx.x * NB + b] + r;
            binned[pos] = make_int2(sN, d);
        }
    }
}

// ---------------- finalize A: per-bucket degree count -> cntg, padded bucket totals ----------------
__global__ __launch_bounds__(256) void finalize_a_kernel(
    const int2* __restrict__ binned, const int* __restrict__ bstart,
    int* __restrict__ cntg, int* __restrict__ ptot, int shift, int n) {
    __shared__ int lc[MAXW];
    __shared__ int ps[256];
    int b = blockIdx.x, tid = threadIdx.x;
    int dbase = b << shift, W = 1 << shift;
    for (int i = tid; i < W; i += 256) lc[i] = 0;
    __syncthreads();
    int beg = bstart[b], end = bstart[b + 1];
    for (int i = beg + tid; i < end; i += 256)
        atomicAdd(&lc[binned[i].y - dbase], 1);
    __syncthreads();
    int chunk = (W + 255) >> 8;
    int s0 = tid * chunk;
    int sum = 0;
    #pragma unroll 8
    for (int j = 0; j < 8; ++j) {
        if (j < chunk) {
            int idx = s0 + j;
            if (idx < W) {
                int c = lc[idx];
                if (dbase + idx < n) cntg[dbase + idx] = c;
                sum += (c + 3) & ~3;
            }
        }
    }
    ps[tid] = sum;
    __syncthreads();
    #pragma unroll
    for (int off = 128; off > 0; off >>= 1) {
        if (tid < off) ps[tid] += ps[tid + off];
        __syncthreads();
    }
    if (tid == 0) ptot[b] = ps[0];
}

// ---------------- finalize B: padded rs/dis, pad-fill, scatter; zero pad rows ----------------
__global__ __launch_bounds__(256) void finalize_b_kernel(
    const int2* __restrict__ binned, const int* __restrict__ bstart,
    const int* __restrict__ cntg, const int* __restrict__ pstart,
    int* __restrict__ rs, float* __restrict__ dis, int* __restrict__ csr,
    f16* __restrict__ HtabPadRow, float* __restrict__ H3, int shift, int n) {
    __shared__ int lc[MAXW];   // padded local prefix -> scatter cursor
    __shared__ int ps[256];
    int b = blockIdx.x, tid = threadIdx.x;
    int dbase = b << shift, W = 1 << shift;
    int pb = pstart[b];
    int chunk = (W + 255) >> 8;
    int s0 = tid * chunk;
    int cc[8];
    int sum = 0;
    #pragma unroll 8
    for (int j = 0; j < 8; ++j) {
        cc[j] = 0;
        if (j < chunk) {
            int idx = s0 + j;
            int c = (idx < W && dbase + idx < n) ? cntg[dbase + idx] : 0;
            cc[j] = c;
            sum += (c + 3) & ~3;
        }
    }
    ps[tid] = sum;
    __syncthreads();
    for (int off = 1; off < 256; off <<= 1) {
        int t = (tid >= off) ? ps[tid - off] : 0;
        __syncthreads();
        ps[tid] += t;
        __syncthreads();
    }
    int pref = (tid == 0) ? 0 : ps[tid - 1];
    #pragma unroll 8
    for (int j = 0; j < 8; ++j) {
        if (j < chunk) {
            int idx = s0 + j;
            if (idx < W) {
                int c = cc[j];
                int pc = (c + 3) & ~3;
                if (dbase + idx < n) {
                    rs[dbase + idx] = pb + pref;
                    dis[dbase + idx] = rsqrtf((float)c + 1.0f);
                    for (int k = c; k < pc; ++k) csr[pb + pref + k] = n;  // sentinel -> zero row
                }
                lc[idx] = pref;
                pref += pc;
            }
        }
    }
    __syncthreads();
    int beg = bstart[b], end = bstart[b + 1];
    for (int i = beg + tid; i < end; i += 256) {
        int2 p = binned[i];
        int pos = pb + atomicAdd(&lc[p.y - dbase], 1);
        csr[pos] = p.x;
    }
    if (b == 0) {
        if (tid < 64) ((unsigned*)HtabPadRow)[tid] = 0;            // zero f16 row n (256B)
        if (tid == 64) { H3[2 * (size_t)n] = 0.f; H3[2 * (size_t)n + 1] = 0.f; }
        if (tid == 65) rs[n] = pstart[NB];
    }
}

// ---------------- W split+transpose (both layers in one launch) ----------------
__global__ void wsplit_kernel(const float* __restrict__ W1, const float* __restrict__ W2,
                              unsigned short* __restrict__ WhT1, unsigned short* __restrict__ WlT1,
                              unsigned short* __restrict__ WhT2, unsigned short* __restrict__ WlT2) {
    int g = blockIdx.x * 256 + threadIdx.x;      // 0..32767
    const float* W = (g < 16384) ? W1 : W2;
    unsigned short* WhT = (g < 16384) ? WhT1 : WhT2;
    unsigned short* WlT = (g < 16384) ? WlT1 : WlT2;
    int idx = g & 16383;
    int k = idx >> 7, c = idx & 127;
    float w = W[idx];
    unsigned int u = __float_as_uint(w);
    unsigned short hi = (unsigned short)(u >> 16);
    float rem = w - __uint_as_float((unsigned int)hi << 16);
    unsigned short lo = (unsigned short)(__float_as_uint(rem) >> 16);
    WhT[c * 128 + k] = hi;
    WlT[c * 128 + k] = lo;
}

// ---------------- split helpers ----------------
__device__ __forceinline__ void splitf(float x, short& h, short& l) {
    unsigned int u = __float_as_uint(x);
    unsigned short hi = (unsigned short)(u >> 16);
    float rem = x - __uint_as_float((unsigned int)hi << 16);
    h = (short)hi;
    l = (short)(__float_as_uint(rem) >> 16);
}

// ---------------- split-bf16 MFMA GEMM, fp16 output; INF16: fp16 or fp32 input ----------------
template<int INF16>
__global__ __launch_bounds__(256) void gemm_mfma_kernel(
    const void* __restrict__ Xv, const unsigned short* __restrict__ WhT,
    const unsigned short* __restrict__ WlT, const float* __restrict__ dis,
    f16* __restrict__ out, int n) {
    __shared__ unsigned short bsh[128 * 128];   // [col][k] bf16 hi, swizzled
    __shared__ unsigned short bsl[128 * 128];   // [col][k] bf16 lo, swizzled
    const int tid = threadIdx.x;

    #pragma unroll
    for (int it = 0; it < 8; ++it) {
        int idx = it * 256 + tid;
        int col = idx >> 4;
        int ch  = idx & 15;
        int byte = (col * 256 + ch * 16) ^ ((col & 7) << 4);
        *(uint4*)((char*)bsh + byte) = ((const uint4*)WhT)[idx];
        *(uint4*)((char*)bsl + byte) = ((const uint4*)WlT)[idx];
    }
    __syncthreads();

    const int lane = tid & 63;
    const int wv = tid >> 6;
    const int rbase = blockIdx.x * 128 + wv * 32;
    const int lr = lane & 15;
    const int lg = lane >> 4;

    f32x4 acc[2][8];
    #pragma unroll
    for (int rt = 0; rt < 2; ++rt)
        #pragma unroll
        for (int ct = 0; ct < 8; ++ct) acc[rt][ct] = (f32x4)0.f;

    #pragma unroll
    for (int kk = 0; kk < 4; ++kk) {
        const int k0 = kk * 32 + lg * 8;
        s16x8 bh[8], bl[8];
        #pragma unroll
        for (int ct = 0; ct < 8; ++ct) {
            int col = ct * 16 + lr;
            int byte = (col * 256 + k0 * 2) ^ ((col & 7) << 4);
            bh[ct] = *(const s16x8*)((const char*)bsh + byte);
            bl[ct] = *(const s16x8*)((const char*)bsl + byte);
        }
        #pragma unroll
        for (int rt = 0; rt < 2; ++rt) {
            int row = rbase + rt * 16 + lr;
            s16x8 ah, al;
            if (INF16) {
                const f16* X = (const f16*)Xv;
                f16x8 a = (f16x8)(f16)0;
                if (row < n) a = *(const f16x8*)&X[(size_t)row * CH + k0];
                #pragma unroll
                for (int j = 0; j < 8; ++j) { short h, l; splitf((float)a[j], h, l); ah[j] = h; al[j] = l; }
            } else {
                const float* X = (const float*)Xv;
                float4 a0 = make_float4(0.f, 0.f, 0.f, 0.f);
                float4 a1 = make_float4(0.f, 0.f, 0.f, 0.f);
                if (row < n) {
                    a0 = *(const float4*)&X[(size_t)row * CH + k0];
                    a1 = *(const float4*)&X[(size_t)row * CH + k0 + 4];
                }
                float v[8] = {a0.x, a0.y, a0.z, a0.w, a1.x, a1.y, a1.z, a1.w};
                #pragma unroll
                for (int j = 0; j < 8; ++j) { short h, l; splitf(v[j], h, l); ah[j] = h; al[j] = l; }
            }
            #pragma unroll
            for (int ct = 0; ct < 8; ++ct) {
                acc[rt][ct] = __builtin_amdgcn_mfma_f32_16x16x32_bf16(ah, bh[ct], acc[rt][ct], 0, 0, 0);
                acc[rt][ct] = __builtin_amdgcn_mfma_f32_16x16x32_bf16(al, bh[ct], acc[rt][ct], 0, 0, 0);
                acc[rt][ct] = __builtin_amdgcn_mfma_f32_16x16x32_bf16(ah, bl[ct], acc[rt][ct], 0, 0, 0);
            }
        }
    }

    #pragma unroll
    for (int rt = 0; rt < 2; ++rt) {
        #pragma unroll
        for (int reg = 0; reg < 4; ++reg) {
            int row = rbase + rt * 16 + lg * 4 + reg;
            if (row < n) {
                float d = dis[row];
                #pragma unroll
                for (int ct = 0; ct < 8; ++ct) {
                    int col = ct * 16 + lr;
                    out[(size_t)row * CH + col] = (f16)(acc[rt][ct][reg] * d);
                }
            }
        }
    }
}

// ---------------- aggregation (128 ch): wave per dst, scalarized indices, padded CSR ----------------
// Mode A (W3c == null): outh[dst][:] = fp16(relu(dis*sum + bias))
// Mode B (W3c != null): fused layer-3 transform -> H3[dst][0:2]
__global__ __launch_bounds__(256) void agg128_kernel(
    const f16* __restrict__ Hs, const int* __restrict__ rs, const int* __restrict__ csr,
    const float* __restrict__ dis, const float* __restrict__ bias,
    f16* __restrict__ outh, int n,
    const float* __restrict__ W3c, float* __restrict__ H3) {
    int dst = blockIdx.x * 4 + (threadIdx.x >> 6);
    dst = __builtin_amdgcn_readfirstlane(dst);      // wave-uniform -> SGPR
    if (dst >= n) return;
    int lane = threadIdx.x & 63;
    int c = lane * 2;
    f16x2 sv = *(const f16x2*)&Hs[(size_t)dst * CH + c];
    float2 acc = make_float2((float)sv.x, (float)sv.y);
    int beg = rs[dst], end = rs[dst + 1];           // padded region, length % 4 == 0
    for (int i = beg; i < end; i += 4) {
        int s0 = csr[i], s1 = csr[i + 1], s2 = csr[i + 2], s3 = csr[i + 3];
        f16x2 v0 = *(const f16x2*)&Hs[(size_t)s0 * CH + c];
        f16x2 v1 = *(const f16x2*)&Hs[(size_t)s1 * CH + c];
        f16x2 v2 = *(const f16x2*)&Hs[(size_t)s2 * CH + c];
        f16x2 v3 = *(const f16x2*)&Hs[(size_t)s3 * CH + c];
        acc.x += ((float)v0.x + (float)v1.x) + ((float)v2.x + (float)v3.x);
        acc.y += ((float)v0.y + (float)v1.y) + ((float)v2.y + (float)v3.y);
    }
    float d = dis[dst];
    float2 b = *(const float2*)&bias[c];
    float o0 = fmaxf(fmaf(acc.x, d, b.x), 0.f);
    float o1 = fmaxf(fmaf(acc.y, d, b.y), 0.f);
    if (W3c == nullptr) {
        f16x2 ov; ov.x = (f16)o0; ov.y = (f16)o1;
        *(f16x2*)&outh[(size_t)dst * CH + c] = ov;
    } else {
        float4 w4 = *(const float4*)&W3c[lane * 4];
        float a0 = o0 * w4.x + o1 * w4.z;
        float a1 = o0 * w4.y + o1 * w4.w;
        #pragma unroll
        for (int off = 32; off > 0; off >>= 1) {
            a0 += __shfl_xor(a0, off, 64);
            a1 += __shfl_xor(a1, off, 64);
        }
        if (lane == 0) {
            H3[dst * 2]     = a0 * d;
            H3[dst * 2 + 1] = a1 * d;
        }
    }
}

// ---------------- layer 3 aggregation (2 ch): thread per dst, padded CSR ----------------
__global__ void agg_out_kernel(const float* __restrict__ H3, const int* __restrict__ rs,
                               const int* __restrict__ csr, const float* __restrict__ dis,
                               const float* __restrict__ b3, float* __restrict__ out, int n) {
    int dst = blockIdx.x * blockDim.x + threadIdx.x;
    if (dst >= n) return;
    float2 acc = *(const float2*)&H3[dst * 2];
    int beg = rs[dst], end = rs[dst + 1];
    for (int i = beg; i < end; i += 4) {
        int s0 = csr[i], s1 = csr[i + 1], s2 = csr[i + 2], s3 = csr[i + 3];
        float2 v0 = *(const float2*)&H3[s0 * 2];
        float2 v1 = *(const float2*)&H3[s1 * 2];
        float2 v2 = *(const float2*)&H3[s2 * 2];
        float2 v3 = *(const float2*)&H3[s3 * 2];
        acc.x += (v0.x + v1.x) + (v2.x + v3.x);
        acc.y += (v0.y + v1.y) + (v2.y + v3.y);
    }
    float d = dis[dst];
    out[dst * 2]     = fmaf(acc.x, d, b3[0]);
    out[dst * 2 + 1] = fmaf(acc.y, d, b3[1]);
}

extern "C" void kernel_launch(void* const* d_in, const int* in_sizes, int n_in,
                              void* d_out, int out_size, void* d_ws, size_t ws_size,
                              hipStream_t stream) {
    const float* x  = (const float*)d_in[0];
    const void*  ei = d_in[1];
    const float* W1 = (const float*)d_in[2];
    const float* b1 = (const float*)d_in[3];
    const float* W2 = (const float*)d_in[4];
    const float* b2 = (const float*)d_in[5];
    const float* W3 = (const float*)d_in[6];
    const float* b3 = (const float*)d_in[7];
    float* out = (float*)d_out;

    const int n = in_sizes[0] / CH;      // 100000
    const int e = in_sizes[1] / 2;       // 1600000

    char* w = (char*)d_ws;
    size_t off = 0;
    auto alloc = [&](size_t bytes) { char* p = w + off; off = (off + bytes + 255) & ~(size_t)255; return p; };
    float* bufA   = (float*)alloc((size_t)n * CH * 4);      // f16 Htab (n+1 rows); aliases `binned`
    float* bufB   = (float*)alloc((size_t)n * CH * 4);      // f16 h1; aliases hist/cntg
    int*   csr    = (int*)  alloc(((size_t)e + 3 * (size_t)n + 64) * 4);   // padded
    float* dis    = (float*)alloc((size_t)n * 4);
    int*   rs     = (int*)  alloc(((size_t)n + 1) * 4);
    float* H3     = (float*)alloc(((size_t)n + 1) * 2 * 4); // +1 zero pad row
    int*   btot   = (int*)  alloc(NB * 4);
    int*   bstart = (int*)  alloc((NB + 1) * 4);
    int*   ptot   = (int*)  alloc(NB * 4);
    int*   pstart = (int*)  alloc((NB + 1) * 4);
    unsigned short* WhT1 = (unsigned short*)alloc(128 * 128 * 2);
    unsigned short* WlT1 = (unsigned short*)alloc(128 * 128 * 2);
    unsigned short* WhT2 = (unsigned short*)alloc(128 * 128 * 2);
    unsigned short* WlT2 = (unsigned short*)alloc(128 * 128 * 2);
    char* zbase   = w + off;
    int*   flag   = (int*)  alloc(256);
    size_t zbytes = (size_t)((w + off) - zbase);

    int2* binned = (int2*)bufA;            // e*8 = 12.8MB
    int*  hist   = (int*)bufB;             // nblk*NB*4 ~ 400KB
    int*  cntg   = (int*)bufB + 512 * NB;  // after hist region (512KB offset)
    f16*  Htab   = (f16*)bufA;             // (n+1)*CH*2 = 25.6MB (after binning done)
    f16*  h1f16  = (f16*)bufB;             // n*CH*2 (after CSR build done)

    int shift = 0;
    while (((n - 1) >> shift) >= NB) ++shift;

    hipMemsetAsync(zbase, 0, zbytes, stream);

    int nwords = 2 * e < 16384 ? 2 * e : 16384;
    detect_kernel<<<8, 1024, 0, stream>>>((const int*)ei, flag, nwords);

    wsplit_kernel<<<128, 256, 0, stream>>>(W1, W2, WhT1, WlT1, WhT2, WlT2);

    // ---- CSR build (bucket-major, padded to %4 with sentinel n) ----
    const int nblk = (e + BCHUNK - 1) / BCHUNK;
    hist_kernel<<<nblk, NB, 0, stream>>>(ei, flag, hist, e, shift);
    scan_col_kernel<<<NB, 512, 0, stream>>>(hist, btot, nblk);
    scan_nb_kernel<<<1, NB, 0, stream>>>(btot, bstart);
    bin_kernel<<<nblk, NB, 0, stream>>>(ei, flag, hist, bstart, binned, e, shift);
    finalize_a_kernel<<<NB, 256, 0, stream>>>(binned, bstart, cntg, ptot, shift, n);
    scan_nb_kernel<<<1, NB, 0, stream>>>(ptot, pstart);
    finalize_b_kernel<<<NB, 256, 0, stream>>>(binned, bstart, cntg, pstart, rs, dis, csr,
                                              Htab + (size_t)n * CH, H3, shift, n);

    const int mfmaGrid = (n + 127) / 128;
    const int aggGrid  = (n + 3) / 4;

    // layer 1  (gemm writes fp16 table into bufA — binned no longer needed)
    gemm_mfma_kernel<0><<<mfmaGrid, 256, 0, stream>>>(x, WhT1, WlT1, dis, Htab, n);
    agg128_kernel<<<aggGrid, 256, 0, stream>>>(Htab, rs, csr, dis, b1, h1f16, n, nullptr, nullptr);
    // layer 2: fp16 input gemm (+ fused layer-3 transform in agg epilogue)
    gemm_mfma_kernel<1><<<mfmaGrid, 256, 0, stream>>>(h1f16, WhT2, WlT2, dis, Htab, n);
    agg128_kernel<<<aggGrid, 256, 0, stream>>>(Htab, rs, csr, dis, b2, nullptr, n, W3, H3);
    // layer 3 aggregation
    agg_out_kernel<<<(n + 255) / 256, 256, 0, stream>>>(H3, rs, csr, dis, b3, out, n);
}